// Round 15
// baseline (598.656 us; speedup 1.0000x reference)
//
#include <hip/hip_runtime.h>
#include <stdint.h>

// f32 I/O, bf16 MFMA internals. Attention v10: KVBLK=32 for 4 blocks/CU
// (40KB LDS, 64 VGPR = 8 waves/SIMD, 768 blocks in one 1024-slot round ->
// no quantization tail). Swapped QK^T, fixed-shift log2 softmax, QBLK=128,
// 4-deep K/V rings (K dist 3, V dist 2), K staged by waves 0-3, V by 4-7.
// RoPE fused in QKV GEMM epilogue. Masked-q rows = mean(V) (reference's
// -1e9 bias absorbs scores in f32 -> exactly uniform attention).

typedef unsigned short u16;
typedef __attribute__((ext_vector_type(4))) float f32x4;
typedef __attribute__((ext_vector_type(8))) short short8;
typedef __attribute__((ext_vector_type(4))) short s16x4;
typedef __attribute__((ext_vector_type(8))) __bf16 bf16x8;

__device__ __forceinline__ float b2f(u16 u){
  union { unsigned int i; float f; } v; v.i = ((unsigned int)u) << 16; return v.f;
}
__device__ __forceinline__ u16 f2b(float f){
  union { float f; unsigned int i; } v; v.f = f;
  unsigned int u = v.i;
  u = u + 0x7FFFu + ((u >> 16) & 1u);   // RNE
  return (u16)(u >> 16);
}
__device__ __forceinline__ f32x4 mfma16(short8 a, short8 b, f32x4 c){
  return __builtin_amdgcn_mfma_f32_16x16x32_bf16(
      __builtin_bit_cast(bf16x8, a), __builtin_bit_cast(bf16x8, b), c, 0, 0, 0);
}
__device__ __forceinline__ void gload16(const void* g, void* l){
  void* gnc = const_cast<void*>(g);
  __builtin_amdgcn_global_load_lds((__attribute__((address_space(1))) void*)gnc,
                                   (__attribute__((address_space(3))) void*)l, 16, 0, 0);
}

// ---------------- merged f32 -> bf16 weight conversion (4 segments) ---------
__global__ __launch_bounds__(256) void cvt4_k(
    const float* __restrict__ s0, u16* __restrict__ d0,
    const float* __restrict__ s1, u16* __restrict__ d1,
    const float* __restrict__ s2, u16* __restrict__ d2,
    const float* __restrict__ s3, u16* __restrict__ d3)
{
  int i = blockIdx.x*256 + threadIdx.x;
  const float* src; u16* dst; int j = i;
  if (j < 442368){ src = s0; dst = d0; }
  else if ((j -= 442368) < 147456){ src = s1; dst = d1; }
  else if ((j -= 147456) < 589824){ src = s2; dst = d2; }
  else { j -= 589824; src = s3; dst = d3; }
  float4 v = *(const float4*)(src + (size_t)j*4);
  s16x4 o; o[0]=(short)f2b(v.x); o[1]=(short)f2b(v.y);
  o[2]=(short)f2b(v.z); o[3]=(short)f2b(v.w);
  *(s16x4*)(dst + (size_t)j*4) = o;
}

// ------- key-bias precompute (fixed shift baked in) + vmean zero ------------
__global__ __launch_bounds__(256) void kbias_k(const int* __restrict__ mask,
                                               float* __restrict__ kb,
                                               float* __restrict__ vm, int n)
{
  int i = blockIdx.x*256 + threadIdx.x;
  if (i < n) kb[i] = mask[i] ? -32.f : -1e30f;
  if (i < 24*64) vm[i] = 0.f;
}

// ---------------- adaLN modulation: mod[b][6*768] = c @ Wada^T + bada --------
__global__ __launch_bounds__(256) void mod_k(const float* __restrict__ c,
    const float* __restrict__ Wada, const float* __restrict__ bada, float* __restrict__ modb)
{
  int o = blockIdx.x*4 + (threadIdx.x >> 6);   // 0..9215
  int l = threadIdx.x & 63;
  int b = o / 4608, j = o - b*4608;
  const float* cp = c + b*768;
  const float* wp = Wada + (size_t)j*768;
  float s = 0.f;
  for (int k = l; k < 768; k += 64) s += cp[k] * wp[k];
  #pragma unroll
  for (int d=1; d<64; d<<=1) s += __shfl_xor(s, d);
  if (l == 0) modb[o] = s + bada[j];
}

// ---------------- LayerNorm (no affine) * w * (1+scale) + shift -> bf16 -----
__global__ __launch_bounds__(256) void ln_mod_k(const float* __restrict__ xin,
    u16* __restrict__ out, const float* __restrict__ lnw, const float* __restrict__ modb,
    int shift_c, int scale_c)
{
  int row = blockIdx.x;             // 0..8191 (b*4096+s)
  int b = row >> 12;
  const float* xp = xin + (size_t)row*768;
  int t = threadIdx.x;
  float v[3]; float s = 0.f, s2 = 0.f;
  #pragma unroll
  for (int i=0;i<3;i++){ float f = xp[t + i*256]; v[i] = f; s += f; s2 += f*f; }
  #pragma unroll
  for (int d=1; d<64; d<<=1){ s += __shfl_xor(s, d); s2 += __shfl_xor(s2, d); }
  __shared__ float rs_[4], rs2_[4];
  int w = t >> 6;
  if ((t & 63) == 0){ rs_[w] = s; rs2_[w] = s2; }
  __syncthreads();
  s  = rs_[0]+rs_[1]+rs_[2]+rs_[3];
  s2 = rs2_[0]+rs2_[1]+rs2_[2]+rs2_[3];
  float mu  = s * (1.f/768.f);
  float var = fmaxf(s2 * (1.f/768.f) - mu*mu, 0.f);
  float rstd = rsqrtf(var + 1e-5f);
  const float* scp = modb + b*4608 + scale_c*768;
  const float* shp = modb + b*4608 + shift_c*768;
  #pragma unroll
  for (int i=0;i<3;i++){
    int d = t + i*256;
    float f = (v[i]-mu)*rstd*lnw[d];
    f = f*(1.f + scp[d]) + shp[d];
    out[(size_t)row*768 + d] = f2b(f);
  }
}

// ---------------- 128x128 BK=64 GEMM, C = A[M,K] @ Bt[N,K]^T, fused epilogues
template<int EPI>
__global__ __launch_bounds__(256) void gemm_k(
    const u16* __restrict__ A, const u16* __restrict__ Bt, void* __restrict__ Cv,
    int M, int N, int K,
    const float* __restrict__ addend, const float* __restrict__ modb,
    const float* __restrict__ bias,
    const float* __restrict__ cosb, const float* __restrict__ sinb,
    u16* __restrict__ qO, u16* __restrict__ kO, u16* __restrict__ vO)
{
  __shared__ __align__(16) u16 As[128*64];
  __shared__ __align__(16) u16 Bs[128*64];
  const int bm = blockIdx.x, bn = blockIdx.y;
  const int tid = threadIdx.x;
  const int w = tid >> 6, l = tid & 63;
  const int wr = w >> 1, wc = w & 1;
  const int l15 = l & 15, lg = l >> 4;
  f32x4 acc[4][4] = {};

  for (int k0 = 0; k0 < K; k0 += 64){
    #pragma unroll
    for (int i=0;i<4;i++){
      int e = i*256 + tid;
      int r = e >> 3, ch = e & 7;
      int sc = ch ^ (r & 7);
      gload16(A  + (size_t)(bm*128 + r)*K + k0 + sc*8, &As[e*8]);
      gload16(Bt + (size_t)(bn*128 + r)*K + k0 + sc*8, &Bs[e*8]);
    }
    __syncthreads();
    #pragma unroll
    for (int kk=0;kk<2;kk++){
      short8 af[4], bfv[4];
      #pragma unroll
      for (int i=0;i<4;i++){
        int ra = wr*64 + i*16 + l15;
        af[i]  = *(const short8*)&As[ra*64 + (((kk*4)+lg) ^ (ra&7))*8];
        int rb = wc*64 + i*16 + l15;
        bfv[i] = *(const short8*)&Bs[rb*64 + (((kk*4)+lg) ^ (rb&7))*8];
      }
      #pragma unroll
      for (int m=0;m<4;m++)
        #pragma unroll
        for (int n=0;n<4;n++)
          acc[m][n] = mfma16(af[m], bfv[n], acc[m][n]);
    }
    __syncthreads();
  }

  if constexpr (EPI == 4){
    const int colseg = bn*128 + wc*64;
    const int qi = colseg / 768;            // 0=q 1=k 2=v
    const int h  = (colseg - qi*768) >> 6;  // 0..11
    const float qs = (qi == 0) ? 0.1803368801111601f : 1.f;  // 0.125*log2(e)
    u16* dst = (qi == 0) ? qO : (qi == 1) ? kO : vO;
    #pragma unroll
    for (int m=0;m<4;m++){
      #pragma unroll
      for (int r=0;r<4;r++){
        int row = bm*128 + wr*64 + m*16 + lg*4 + r;
        int s = row & 4095, bb = row >> 12;
        size_t obase = ((size_t)(bb*12 + h)*4096 + s)*64;
        #pragma unroll
        for (int n2=0;n2<2;n2++){
          int d1 = n2*16 + l15;            // < 32
          int d2 = d1 + 32;
          float c1 = cosb[s*64 + d1], s1 = sinb[s*64 + d1];
          float c2 = cosb[s*64 + d2], s2 = sinb[s*64 + d2];
          float x1 = acc[m][n2][r], x2 = acc[m][n2+2][r];
          dst[obase + d1] = f2b((x1*c1 - x2*s1)*qs);
          dst[obase + d2] = f2b((x2*c2 + x1*s2)*qs);
        }
      }
    }
    return;
  }

  #pragma unroll
  for (int m=0;m<4;m++){
    int row0 = bm*128 + wr*64 + m*16 + lg*4;
    #pragma unroll
    for (int n=0;n<4;n++){
      int col = bn*128 + wc*64 + n*16 + l15;
      #pragma unroll
      for (int r=0;r<4;r++){
        int row = row0 + r;
        size_t idx = (size_t)row*N + col;
        float v = acc[m][n][r];
        if constexpr (EPI == 0){
          ((u16*)Cv)[idx] = f2b(v);
        } else if constexpr (EPI == 1){
          float g = modb[(row>>12)*4608 + 2*768 + col];   // gate_msa
          ((float*)Cv)[idx] = addend[idx] + g*v;
        } else if constexpr (EPI == 2){
          float u = v + bias[col];
          float t0 = 0.7978845608028654f*(u + 0.044715f*u*u*u);
          ((u16*)Cv)[idx] = f2b(0.5f*u*(1.0f + tanhf(t0)));
        } else if constexpr (EPI == 3){
          float g = modb[(row>>12)*4608 + 5*768 + col];   // gate_mlp
          float u = v + bias[col];
          ((float*)Cv)[idx] = addend[idx] + g*u;
        }
      }
    }
  }
}

// ---------------- V transpose + column-sum atomics --------------------------
__global__ __launch_bounds__(256) void vtr_k(const u16* __restrict__ vS,
                                             u16* __restrict__ vT,
                                             float* __restrict__ vm)
{
  __shared__ __align__(16) u16 tile[64][72];
  __shared__ float cs[4][64];
  int st = blockIdx.x, bh = blockIdx.y;
  int t = threadIdx.x;
  #pragma unroll
  for (int i=0;i<2;i++){
    int e = i*256 + t;
    int r = e >> 3, d0 = (e & 7)*8;
    short8 vv = *(const short8*)(vS + ((size_t)bh*4096 + st*64 + r)*64 + d0);
    *(short8*)&tile[r][d0] = vv;
  }
  __syncthreads();
  #pragma unroll
  for (int i=0;i<2;i++){
    int e = i*256 + t;
    int d = e >> 3, s0 = (e & 7)*8;
    short8 ov;
    #pragma unroll
    for (int k2=0;k2<8;k2++) ov[k2] = (short)tile[s0+k2][d];
    *(short8*)(vT + ((size_t)bh*64 + d)*4096 + st*64 + s0) = ov;
  }
  int d = t & 63, qq = t >> 6;
  float s = 0.f;
  #pragma unroll
  for (int i=0;i<16;i++) s += b2f(tile[qq*16 + i][d]);
  cs[qq][d] = s;
  __syncthreads();
  if (qq == 0) atomicAdd(&vm[bh*64 + d], cs[0][d]+cs[1][d]+cs[2][d]+cs[3][d]);
}

// ---------------- flash attention v10: KVBLK=32, 4 blocks/CU ----------------
// 128 bodies. KQK=(KT+1)%4, KST=(KT+3)%4, VPV=KT%4, VST=(KT+2)%4.
// Waves 0-3 stage K tile (32 rows x 64d), waves 4-7 stage V tile (64d x 32s).
#define AT_BODY(KT, KQK, KST, VPV, VST, STC, STN)                              \
{                                                                              \
  f32x4 kb_[2];                                                                \
  _Pragma("unroll")                                                            \
  for (int n=0;n<2;n++)                                                        \
    kb_[n] = *(const f32x4*)(kbrow + (KT)*32 + n*16 + lg*4);                   \
  __builtin_amdgcn_sched_barrier(0);  /* pin kb issue before stage gload */    \
  if (tid < 256){                                                              \
    int k3 = (KT)+3 < 128 ? (KT)+3 : 127;                                      \
    gload16(kbase + (size_t)(k3*32 + rk)*64 + kssc*8, &Ks[KST][tid*8]);        \
  } else {                                                                     \
    int v2 = (KT)+2 < 128 ? (KT)+2 : 127;                                      \
    gload16(vbase + (size_t)dv*4096 + v2*32 + vssc*8, &Vs[VST][ut*8]);         \
  }                                                                            \
  if ((KT)+1 < 128){                                                           \
    __builtin_amdgcn_s_setprio(1);                                             \
    _Pragma("unroll")                                                          \
    for (int n=0;n<2;n++){                                                     \
      int R = n*16 + l15;                                                      \
      f32x4 a_ = {};                                                           \
      _Pragma("unroll")                                                        \
      for (int kk=0;kk<2;kk++){                                                \
        short8 ka = *(const short8*)&Ks[KQK][R*64 + (((kk<<2)+lg) ^ (R&7))*8]; \
      a_ = mfma16(ka, bq[kk], a_);                                             \
      }                                                                        \
      STN[n] = a_;                                                             \
    }                                                                          \
    __builtin_amdgcn_s_setprio(0);                                             \
  }                                                                            \
  float p_[2][4]; float ts_ = 0.f;                                             \
  _Pragma("unroll")                                                            \
  for (int n=0;n<2;n++)                                                        \
    _Pragma("unroll")                                                          \
    for (int r=0;r<4;r++){                                                     \
      float e_ = __builtin_amdgcn_exp2f(STC[n][r] + kb_[n][r]);                \
      p_[n][r] = e_; ts_ += e_;                                                \
    }                                                                          \
  ts_ += __shfl_xor(ts_, 16);                                                  \
  ts_ += __shfl_xor(ts_, 32);                                                  \
  l_run += ts_;                                                                \
  _Pragma("unroll")                                                            \
  for (int n=0;n<2;n++){                                                       \
    unsigned p01_, p23_;                                                       \
    asm("v_cvt_pk_bf16_f32 %0, %1, %2" : "=v"(p01_) : "v"(p_[n][0]), "v"(p_[n][1])); \
    asm("v_cvt_pk_bf16_f32 %0, %1, %2" : "=v"(p23_) : "v"(p_[n][2]), "v"(p_[n][3])); \
    int s0_ = n*16 + lg*4;                                                     \
    int off_ = (((s0_>>3) ^ (l15&3))<<3) + (s0_&7);                            \
    *(unsigned*)&Ps[w][l15*32 + off_]     = p01_;                              \
    *(unsigned*)&Ps[w][l15*32 + off_ + 2] = p23_;                              \
  }                                                                            \
  __builtin_amdgcn_s_setprio(1);                                               \
  {                                                                            \
    short8 bp_ = *(const short8*)&Ps[w][l15*32 + ((lg ^ (l15&3))<<3)];         \
    _Pragma("unroll")                                                          \
    for (int n=0;n<4;n++){                                                     \
      int R = n*16 + l15;                                                      \
      short8 va_ = *(const short8*)&Vs[VPV][R*32 + ((lg ^ (R&3))<<3)];         \
      oacc[n] = mfma16(va_, bp_, oacc[n]);                                     \
    }                                                                          \
  }                                                                            \
  __builtin_amdgcn_s_setprio(0);                                               \
  __builtin_amdgcn_s_barrier();                                                \
}

__global__ __launch_bounds__(512, 8) void attn_k(
    const u16* __restrict__ qT, const u16* __restrict__ kT, const u16* __restrict__ vT,
    const int* __restrict__ mask, const float* __restrict__ kbias,
    const float* __restrict__ vmean, u16* __restrict__ o)
{
  __shared__ __align__(16) u16 Ks[4][32*64];
  __shared__ __align__(16) u16 Vs[4][64*32];
  __shared__ __align__(16) u16 Ps[8][16*32];
  const int qt = blockIdx.x, bh = blockIdx.y;
  const int b = bh / 12, h = bh - b*12;
  const int tid = threadIdx.x, w = tid >> 6, l = tid & 63;
  const int l15 = l & 15, lg = l >> 4;

  short8 bq[2];
  {
    const u16* qp = qT + ((size_t)bh*4096 + qt*128 + w*16 + l15)*64 + lg*8;
    bq[0] = *(const short8*)qp;
    bq[1] = *(const short8*)(qp + 32);
  }
  const bool fq = mask[b*4096 + qt*128 + w*16 + l15] != 0;
  const float* kbrow = kbias + b*4096;
  const u16* kbase = kT + (size_t)bh*4096*64;
  const u16* vbase = vT + (size_t)bh*64*4096;

  float l_run = 0.f;
  f32x4 oacc[4] = {};   // O^T[d = n*16+lg*4+r][q = l15]

  // staging geometry: tid<256 -> K tile rows (rk 0..31, 8 chunks of 16B);
  //                   tid>=256 -> V tile rows (dv 0..63, 4 chunks of 16B)
  const int rk = tid >> 3, kssc = (tid & 7) ^ (rk & 7);
  const int ut = tid & 255, dv = ut >> 2, vssc = (ut & 3) ^ (dv & 3);

  // prologue: stage K0,K1,K2 / V0,V1; drain; QK^T(0)
  if (tid < 256){
    gload16(kbase + (size_t)(  0 + rk)*64 + kssc*8, &Ks[0][tid*8]);
    gload16(kbase + (size_t)( 32 + rk)*64 + kssc*8, &Ks[1][tid*8]);
    gload16(kbase + (size_t)( 64 + rk)*64 + kssc*8, &Ks[2][tid*8]);
  } else {
    gload16(vbase + (size_t)dv*4096 +  0 + vssc*8, &Vs[0][ut*8]);
    gload16(vbase + (size_t)dv*4096 + 32 + vssc*8, &Vs[1][ut*8]);
  }
  asm volatile("s_waitcnt vmcnt(0)" ::: "memory");
  __builtin_amdgcn_s_barrier();

  f32x4 stA[2], stB[2];
  #pragma unroll
  for (int n=0;n<2;n++){
    int R = n*16 + l15;
    f32x4 a_ = {};
    #pragma unroll
    for (int kk=0;kk<2;kk++){
      short8 ka = *(const short8*)&Ks[0][R*64 + (((kk<<2)+lg) ^ (R&7))*8];
      a_ = mfma16(ka, bq[kk], a_);
    }
    stA[n] = a_;
  }
  // no extra barrier: Ks[0] first overwritten in body 1 (after body 0's
  // end barrier), and all waves finish this read before body 0's barrier.

  for (int kt = 0; kt < 128; kt += 4){
    AT_BODY(kt+0, 1, 3, 0, 2, stA, stB)
    AT_BODY(kt+1, 2, 0, 1, 3, stB, stA)
    AT_BODY(kt+2, 3, 1, 2, 0, stA, stB)
    AT_BODY(kt+3, 0, 2, 3, 1, stB, stA)
  }

  float inv = 1.f / l_run;
  size_t base = ((size_t)b*4096 + qt*128 + w*16 + l15)*768 + h*64 + lg*4;
  #pragma unroll
  for (int n=0;n<4;n++){
    f32x4 vm = *(const f32x4*)(vmean + bh*64 + n*16 + lg*4);
    float v0 = fq ? oacc[n][0]*inv : vm[0]*(1.f/4096.f);
    float v1 = fq ? oacc[n][1]*inv : vm[1]*(1.f/4096.f);
    float v2 = fq ? oacc[n][2]*inv : vm[2]*(1.f/4096.f);
    float v3 = fq ? oacc[n][3]*inv : vm[3]*(1.f/4096.f);
    unsigned q01 = (unsigned)f2b(v0) | ((unsigned)f2b(v1) << 16);
    unsigned q23 = (unsigned)f2b(v2) | ((unsigned)f2b(v3) << 16);
    *(unsigned*)&o[base + n*16]     = q01;
    *(unsigned*)&o[base + n*16 + 2] = q23;
  }
}

// ---------------------------------------------------------------------------
extern "C" void kernel_launch(void* const* d_in, const int* in_sizes, int n_in,
                              void* d_out, int out_size, void* d_ws, size_t ws_size,
                              hipStream_t stream)
{
  const float* x    = (const float*)d_in[0];
  const float* cosb = (const float*)d_in[1];
  const float* sinb = (const float*)d_in[2];
  const float* c    = (const float*)d_in[3];
  const int* amask  = (const int*)d_in[4];
  const float* ln1w = (const float*)d_in[5];
  const float* Wqkv = (const float*)d_in[6];
  const float* Wout = (const float*)d_in[7];
  const float* ln2w = (const float*)d_in[8];
  const float* W1   = (const float*)d_in[9];
  const float* b1   = (const float*)d_in[10];
  const float* W2   = (const float*)d_in[11];
  const float* b2   = (const float*)d_in[12];
  const float* Wada = (const float*)d_in[13];
  const float* bada = (const float*)d_in[14];

  char* ws = (char*)d_ws;
  size_t off = 0;
  auto take = [&](size_t bytes)->char*{
    char* p = ws + off; off = (off + bytes + 255) & ~(size_t)255; return p;
  };
  float* modb = (float*)take(9216*sizeof(float));
  float* kbias= (float*)take(8192*sizeof(float));
  float* vmean= (float*)take(24*64*sizeof(float));
  u16* hdn  = (u16*)take((size_t)8192*768*2);    // hdn, then h2 (bf16)
  u16* bufA = (u16*)take((size_t)8192*3072*2);   // MLP mid (bf16)
  u16* vS   = (u16*)take((size_t)8192*768*2);    // v (s-major)
  u16* qTb  = (u16*)take((size_t)8192*768*2);
  u16* kTb  = (u16*)take((size_t)8192*768*2);
  u16* vTb  = (u16*)take((size_t)8192*768*2);    // v (d-major)
  u16* ob   = (u16*)take((size_t)8192*768*2);    // attention output (bf16)
  u16* WqkvB= (u16*)take((size_t)2304*768*2);
  u16* WoutB= (u16*)take((size_t)768*768*2);
  u16* W1B  = (u16*)take((size_t)3072*768*2);
  u16* W2B  = (u16*)take((size_t)768*3072*2);
  float* out = (float*)d_out;
  float* x1 = out;                               // reuse d_out for x1 (f32)

  cvt4_k<<<6912, 256, 0, stream>>>(Wqkv, WqkvB, Wout, WoutB, W1, W1B, W2, W2B);
  kbias_k<<<32, 256, 0, stream>>>(amask, kbias, vmean, 8192);

  mod_k  <<<2304, 256, 0, stream>>>(c, Wada, bada, modb);
  ln_mod_k<<<8192, 256, 0, stream>>>(x, hdn, ln1w, modb, 0, 1);
  gemm_k<4><<<dim3(64,18), 256, 0, stream>>>(hdn, WqkvB, nullptr, 8192, 2304, 768,
                                             nullptr, nullptr, nullptr,
                                             cosb, sinb, qTb, kTb, vS);
  vtr_k  <<<dim3(64,24), 256, 0, stream>>>(vS, vTb, vmean);
  attn_k <<<dim3(32,24), 512, 0, stream>>>(qTb, kTb, vTb, amask, kbias, vmean, ob);
  gemm_k<1><<<dim3(64,6), 256, 0, stream>>>(ob, WoutB, x1, 8192, 768, 768,
                                            x, modb, nullptr,
                                            nullptr, nullptr, nullptr, nullptr, nullptr);
  ln_mod_k<<<8192, 256, 0, stream>>>(x1, hdn, ln2w, modb, 3, 4);
  gemm_k<2><<<dim3(64,24), 256, 0, stream>>>(hdn, W1B, bufA, 8192, 3072, 768,
                                             nullptr, nullptr, b1,
                                             nullptr, nullptr, nullptr, nullptr, nullptr);
  gemm_k<3><<<dim3(64,6), 256, 0, stream>>>(bufA, W2B, out, 8192, 768, 3072,
                                            x1, modb, b2,
                                            nullptr, nullptr, nullptr, nullptr, nullptr);
}

// Round 16
// 396.644 us; speedup vs baseline: 1.5093x; 1.5093x over previous
//
#include <hip/hip_runtime.h>
#include <stdint.h>

// f32 I/O, bf16 MFMA internals. Attention v11 = r14 body (known good, 80KB,
// 8 waves, 4-deep rings, fixed-shift log2 softmax) + KV-SPLIT x2: grid
// (32,24,2), each block does half the key range; fixed shift makes partials
// exactly addable: O = (O0+O1)/(l0+l1). Partials in f32 (alias bufA/hdn),
// comb_k divides + handles masked-q rows (= mean(V), since reference's -1e9
// bias absorbs scores in f32). 1536 blocks = exactly 3 rounds of 512 slots
// -> no occupancy tail (was 2 rounds [512,256]).

typedef unsigned short u16;
typedef __attribute__((ext_vector_type(4))) float f32x4;
typedef __attribute__((ext_vector_type(8))) short short8;
typedef __attribute__((ext_vector_type(4))) short s16x4;
typedef __attribute__((ext_vector_type(8))) __bf16 bf16x8;

__device__ __forceinline__ float b2f(u16 u){
  union { unsigned int i; float f; } v; v.i = ((unsigned int)u) << 16; return v.f;
}
__device__ __forceinline__ u16 f2b(float f){
  union { float f; unsigned int i; } v; v.f = f;
  unsigned int u = v.i;
  u = u + 0x7FFFu + ((u >> 16) & 1u);   // RNE
  return (u16)(u >> 16);
}
__device__ __forceinline__ f32x4 mfma16(short8 a, short8 b, f32x4 c){
  return __builtin_amdgcn_mfma_f32_16x16x32_bf16(
      __builtin_bit_cast(bf16x8, a), __builtin_bit_cast(bf16x8, b), c, 0, 0, 0);
}
__device__ __forceinline__ void gload16(const void* g, void* l){
  void* gnc = const_cast<void*>(g);
  __builtin_amdgcn_global_load_lds((__attribute__((address_space(1))) void*)gnc,
                                   (__attribute__((address_space(3))) void*)l, 16, 0, 0);
}

// ---------------- merged f32 -> bf16 weight conversion (4 segments) ---------
__global__ __launch_bounds__(256) void cvt4_k(
    const float* __restrict__ s0, u16* __restrict__ d0,
    const float* __restrict__ s1, u16* __restrict__ d1,
    const float* __restrict__ s2, u16* __restrict__ d2,
    const float* __restrict__ s3, u16* __restrict__ d3)
{
  int i = blockIdx.x*256 + threadIdx.x;
  const float* src; u16* dst; int j = i;
  if (j < 442368){ src = s0; dst = d0; }
  else if ((j -= 442368) < 147456){ src = s1; dst = d1; }
  else if ((j -= 147456) < 589824){ src = s2; dst = d2; }
  else { j -= 589824; src = s3; dst = d3; }
  float4 v = *(const float4*)(src + (size_t)j*4);
  s16x4 o; o[0]=(short)f2b(v.x); o[1]=(short)f2b(v.y);
  o[2]=(short)f2b(v.z); o[3]=(short)f2b(v.w);
  *(s16x4*)(dst + (size_t)j*4) = o;
}

// ------- key-bias precompute (fixed shift baked in) + vmean zero ------------
__global__ __launch_bounds__(256) void kbias_k(const int* __restrict__ mask,
                                               float* __restrict__ kb,
                                               float* __restrict__ vm, int n)
{
  int i = blockIdx.x*256 + threadIdx.x;
  if (i < n) kb[i] = mask[i] ? -32.f : -1e30f;
  if (i < 24*64) vm[i] = 0.f;
}

// ---------------- adaLN modulation: mod[b][6*768] = c @ Wada^T + bada --------
__global__ __launch_bounds__(256) void mod_k(const float* __restrict__ c,
    const float* __restrict__ Wada, const float* __restrict__ bada, float* __restrict__ modb)
{
  int o = blockIdx.x*4 + (threadIdx.x >> 6);   // 0..9215
  int l = threadIdx.x & 63;
  int b = o / 4608, j = o - b*4608;
  const float* cp = c + b*768;
  const float* wp = Wada + (size_t)j*768;
  float s = 0.f;
  for (int k = l; k < 768; k += 64) s += cp[k] * wp[k];
  #pragma unroll
  for (int d=1; d<64; d<<=1) s += __shfl_xor(s, d);
  if (l == 0) modb[o] = s + bada[j];
}

// ---------------- LayerNorm (no affine) * w * (1+scale) + shift -> bf16 -----
__global__ __launch_bounds__(256) void ln_mod_k(const float* __restrict__ xin,
    u16* __restrict__ out, const float* __restrict__ lnw, const float* __restrict__ modb,
    int shift_c, int scale_c)
{
  int row = blockIdx.x;             // 0..8191 (b*4096+s)
  int b = row >> 12;
  const float* xp = xin + (size_t)row*768;
  int t = threadIdx.x;
  float v[3]; float s = 0.f, s2 = 0.f;
  #pragma unroll
  for (int i=0;i<3;i++){ float f = xp[t + i*256]; v[i] = f; s += f; s2 += f*f; }
  #pragma unroll
  for (int d=1; d<64; d<<=1){ s += __shfl_xor(s, d); s2 += __shfl_xor(s2, d); }
  __shared__ float rs_[4], rs2_[4];
  int w = t >> 6;
  if ((t & 63) == 0){ rs_[w] = s; rs2_[w] = s2; }
  __syncthreads();
  s  = rs_[0]+rs_[1]+rs_[2]+rs_[3];
  s2 = rs2_[0]+rs2_[1]+rs2_[2]+rs2_[3];
  float mu  = s * (1.f/768.f);
  float var = fmaxf(s2 * (1.f/768.f) - mu*mu, 0.f);
  float rstd = rsqrtf(var + 1e-5f);
  const float* scp = modb + b*4608 + scale_c*768;
  const float* shp = modb + b*4608 + shift_c*768;
  #pragma unroll
  for (int i=0;i<3;i++){
    int d = t + i*256;
    float f = (v[i]-mu)*rstd*lnw[d];
    f = f*(1.f + scp[d]) + shp[d];
    out[(size_t)row*768 + d] = f2b(f);
  }
}

// ---------------- 128x128 BK=64 GEMM, C = A[M,K] @ Bt[N,K]^T, fused epilogues
template<int EPI>
__global__ __launch_bounds__(256) void gemm_k(
    const u16* __restrict__ A, const u16* __restrict__ Bt, void* __restrict__ Cv,
    int M, int N, int K,
    const float* __restrict__ addend, const float* __restrict__ modb,
    const float* __restrict__ bias,
    const float* __restrict__ cosb, const float* __restrict__ sinb,
    u16* __restrict__ qO, u16* __restrict__ kO, u16* __restrict__ vO)
{
  __shared__ __align__(16) u16 As[128*64];
  __shared__ __align__(16) u16 Bs[128*64];
  const int bm = blockIdx.x, bn = blockIdx.y;
  const int tid = threadIdx.x;
  const int w = tid >> 6, l = tid & 63;
  const int wr = w >> 1, wc = w & 1;
  const int l15 = l & 15, lg = l >> 4;
  f32x4 acc[4][4] = {};

  for (int k0 = 0; k0 < K; k0 += 64){
    #pragma unroll
    for (int i=0;i<4;i++){
      int e = i*256 + tid;
      int r = e >> 3, ch = e & 7;
      int sc = ch ^ (r & 7);
      gload16(A  + (size_t)(bm*128 + r)*K + k0 + sc*8, &As[e*8]);
      gload16(Bt + (size_t)(bn*128 + r)*K + k0 + sc*8, &Bs[e*8]);
    }
    __syncthreads();
    #pragma unroll
    for (int kk=0;kk<2;kk++){
      short8 af[4], bfv[4];
      #pragma unroll
      for (int i=0;i<4;i++){
        int ra = wr*64 + i*16 + l15;
        af[i]  = *(const short8*)&As[ra*64 + (((kk*4)+lg) ^ (ra&7))*8];
        int rb = wc*64 + i*16 + l15;
        bfv[i] = *(const short8*)&Bs[rb*64 + (((kk*4)+lg) ^ (rb&7))*8];
      }
      #pragma unroll
      for (int m=0;m<4;m++)
        #pragma unroll
        for (int n=0;n<4;n++)
          acc[m][n] = mfma16(af[m], bfv[n], acc[m][n]);
    }
    __syncthreads();
  }

  if constexpr (EPI == 4){
    const int colseg = bn*128 + wc*64;
    const int qi = colseg / 768;            // 0=q 1=k 2=v
    const int h  = (colseg - qi*768) >> 6;  // 0..11
    const float qs = (qi == 0) ? 0.1803368801111601f : 1.f;  // 0.125*log2(e)
    u16* dst = (qi == 0) ? qO : (qi == 1) ? kO : vO;
    #pragma unroll
    for (int m=0;m<4;m++){
      #pragma unroll
      for (int r=0;r<4;r++){
        int row = bm*128 + wr*64 + m*16 + lg*4 + r;
        int s = row & 4095, bb = row >> 12;
        size_t obase = ((size_t)(bb*12 + h)*4096 + s)*64;
        #pragma unroll
        for (int n2=0;n2<2;n2++){
          int d1 = n2*16 + l15;            // < 32
          int d2 = d1 + 32;
          float c1 = cosb[s*64 + d1], s1 = sinb[s*64 + d1];
          float c2 = cosb[s*64 + d2], s2 = sinb[s*64 + d2];
          float x1 = acc[m][n2][r], x2 = acc[m][n2+2][r];
          dst[obase + d1] = f2b((x1*c1 - x2*s1)*qs);
          dst[obase + d2] = f2b((x2*c2 + x1*s2)*qs);
        }
      }
    }
    return;
  }

  #pragma unroll
  for (int m=0;m<4;m++){
    int row0 = bm*128 + wr*64 + m*16 + lg*4;
    #pragma unroll
    for (int n=0;n<4;n++){
      int col = bn*128 + wc*64 + n*16 + l15;
      #pragma unroll
      for (int r=0;r<4;r++){
        int row = row0 + r;
        size_t idx = (size_t)row*N + col;
        float v = acc[m][n][r];
        if constexpr (EPI == 0){
          ((u16*)Cv)[idx] = f2b(v);
        } else if constexpr (EPI == 1){
          float g = modb[(row>>12)*4608 + 2*768 + col];   // gate_msa
          ((float*)Cv)[idx] = addend[idx] + g*v;
        } else if constexpr (EPI == 2){
          float u = v + bias[col];
          float t0 = 0.7978845608028654f*(u + 0.044715f*u*u*u);
          ((u16*)Cv)[idx] = f2b(0.5f*u*(1.0f + tanhf(t0)));
        } else if constexpr (EPI == 3){
          float g = modb[(row>>12)*4608 + 5*768 + col];   // gate_mlp
          float u = v + bias[col];
          ((float*)Cv)[idx] = addend[idx] + g*u;
        }
      }
    }
  }
}

// ---------------- V transpose + column-sum atomics --------------------------
__global__ __launch_bounds__(256) void vtr_k(const u16* __restrict__ vS,
                                             u16* __restrict__ vT,
                                             float* __restrict__ vm)
{
  __shared__ __align__(16) u16 tile[64][72];
  __shared__ float cs[4][64];
  int st = blockIdx.x, bh = blockIdx.y;
  int t = threadIdx.x;
  #pragma unroll
  for (int i=0;i<2;i++){
    int e = i*256 + t;
    int r = e >> 3, d0 = (e & 7)*8;
    short8 vv = *(const short8*)(vS + ((size_t)bh*4096 + st*64 + r)*64 + d0);
    *(short8*)&tile[r][d0] = vv;
  }
  __syncthreads();
  #pragma unroll
  for (int i=0;i<2;i++){
    int e = i*256 + t;
    int d = e >> 3, s0 = (e & 7)*8;
    short8 ov;
    #pragma unroll
    for (int k2=0;k2<8;k2++) ov[k2] = (short)tile[s0+k2][d];
    *(short8*)(vT + ((size_t)bh*64 + d)*4096 + st*64 + s0) = ov;
  }
  int d = t & 63, qq = t >> 6;
  float s = 0.f;
  #pragma unroll
  for (int i=0;i<16;i++) s += b2f(tile[qq*16 + i][d]);
  cs[qq][d] = s;
  __syncthreads();
  if (qq == 0) atomicAdd(&vm[bh*64 + d], cs[0][d]+cs[1][d]+cs[2][d]+cs[3][d]);
}

// ---------------- flash attention v11: r14 body + KV split ------------------
// KQK=(KT+1)%4, KST=(KT+3)%4, VPV=KT%4, VST=(KT+2)%4 (KT relative to k0%4==0)
#define AT_BODY(KT, KQK, KST, VPV, VST, STC, STN)                              \
{                                                                              \
  f32x4 kb_[4];                                                                \
  _Pragma("unroll")                                                            \
  for (int n=0;n<4;n++)                                                        \
    kb_[n] = *(const f32x4*)(kbrow + (KT)*64 + n*16 + lg*4);                   \
  __builtin_amdgcn_sched_barrier(0);  /* pin kb issue before K/V gloads */     \
  { int k3 = (KT)+3 < kend ? (KT)+3 : kend-1;                                  \
    gload16(kbase + (size_t)(k3*64+sr)*64 + ssc*8, &Ks[KST][tid*8]); }         \
  { int v2 = (KT)+2 < kend ? (KT)+2 : kend-1;                                  \
    gload16(vbase + (size_t)sr*4096 + v2*64 + ssc*8, &Vs[VST][tid*8]); }       \
  if ((KT)+1 < kend){                                                          \
    __builtin_amdgcn_s_setprio(1);                                             \
    _Pragma("unroll")                                                          \
    for (int n=0;n<4;n++){                                                     \
      int R = n*16 + l15;                                                      \
      f32x4 a_ = {};                                                           \
      _Pragma("unroll")                                                        \
      for (int kk=0;kk<2;kk++){                                                \
        short8 ka = *(const short8*)&Ks[KQK][R*64 + (((kk<<2)+lg) ^ (R&7))*8]; \
        a_ = mfma16(ka, bq[kk], a_);                                           \
      }                                                                        \
      STN[n] = a_;                                                             \
    }                                                                          \
    __builtin_amdgcn_s_setprio(0);                                             \
  }                                                                            \
  /* compiler inserts vmcnt for kb_ use: retires prev body's K/V */            \
  float p_[4][4]; float ts_ = 0.f;                                             \
  _Pragma("unroll")                                                            \
  for (int n=0;n<4;n++)                                                        \
    _Pragma("unroll")                                                          \
    for (int r=0;r<4;r++){                                                     \
      float e_ = __builtin_amdgcn_exp2f(STC[n][r] + kb_[n][r]);                \
      p_[n][r] = e_; ts_ += e_;                                                \
    }                                                                          \
  ts_ += __shfl_xor(ts_, 16);                                                  \
  ts_ += __shfl_xor(ts_, 32);                                                  \
  l_run += ts_;                                                                \
  _Pragma("unroll")                                                            \
  for (int n=0;n<4;n++){                                                       \
    unsigned p01_, p23_;                                                       \
    asm("v_cvt_pk_bf16_f32 %0, %1, %2" : "=v"(p01_) : "v"(p_[n][0]), "v"(p_[n][1])); \
    asm("v_cvt_pk_bf16_f32 %0, %1, %2" : "=v"(p23_) : "v"(p_[n][2]), "v"(p_[n][3])); \
    int s0_ = n*16 + lg*4;                                                     \
    int off_ = (((s0_>>3) ^ (l15&7))<<3) + (s0_&7);                            \
    *(unsigned*)&Ps[w][l15*64 + off_]     = p01_;                              \
    *(unsigned*)&Ps[w][l15*64 + off_ + 2] = p23_;                              \
  }                                                                            \
  __builtin_amdgcn_s_setprio(1);                                               \
  _Pragma("unroll")                                                            \
  for (int kk=0;kk<2;kk++){                                                    \
    int ch_ = (kk<<2) + lg;                                                    \
    short8 bp_ = *(const short8*)&Ps[w][l15*64 + ((ch_ ^ (l15&7))<<3)];        \
    _Pragma("unroll")                                                          \
    for (int n=0;n<4;n++){                                                     \
      int R = n*16 + l15;                                                      \
      short8 va_ = *(const short8*)&Vs[VPV][R*64 + ((ch_ ^ (R&7))<<3)];        \
      oacc[n] = mfma16(va_, bp_, oacc[n]);                                     \
    }                                                                          \
  }                                                                            \
  __builtin_amdgcn_s_setprio(0);                                               \
  __builtin_amdgcn_s_barrier();                                                \
}

__global__ __launch_bounds__(512) void attn_k(
    const u16* __restrict__ qT, const u16* __restrict__ kT, const u16* __restrict__ vT,
    const float* __restrict__ kbias, float* __restrict__ po, float* __restrict__ pl)
{
  __shared__ __align__(16) u16 Ks[4][64*64];
  __shared__ __align__(16) u16 Vs[4][64*64];
  __shared__ __align__(16) u16 Ps[8][16*64];
  const int qt = blockIdx.x, bh = blockIdx.y, kv = blockIdx.z;
  const int b = bh / 12;
  const int tid = threadIdx.x, w = tid >> 6, l = tid & 63;
  const int l15 = l & 15, lg = l >> 4;
  const int k0 = kv*32, kend = k0 + 32;     // 32 bodies per block

  short8 bq[2];
  {
    const u16* qp = qT + ((size_t)bh*4096 + qt*128 + w*16 + l15)*64 + lg*8;
    bq[0] = *(const short8*)qp;
    bq[1] = *(const short8*)(qp + 32);
  }
  const float* kbrow = kbias + b*4096 + k0*64;   // relative KT*64 indexing
  const u16* kbase = kT + (size_t)bh*4096*64 + (size_t)k0*64*64;
  const u16* vbase = vT + (size_t)bh*64*4096 + (size_t)k0*64;

  float l_run = 0.f;
  f32x4 oacc[4] = {};   // O^T[d = n*16+lg*4+r][q = l15]

  const int sr = tid >> 3, ssc = (tid & 7) ^ (sr & 7);

  // prologue: stage K0,K1,K2,V0,V1 (relative); drain; QK^T(0)
  gload16(kbase + (size_t)sr*64 + ssc*8,            &Ks[0][tid*8]);
  gload16(kbase + (size_t)(64+sr)*64 + ssc*8,       &Ks[1][tid*8]);
  gload16(kbase + (size_t)(128+sr)*64 + ssc*8,      &Ks[2][tid*8]);
  gload16(vbase + (size_t)sr*4096 + ssc*8,          &Vs[0][tid*8]);
  gload16(vbase + (size_t)sr*4096 + 64 + ssc*8,     &Vs[1][tid*8]);
  asm volatile("s_waitcnt vmcnt(0)" ::: "memory");
  __builtin_amdgcn_s_barrier();

  f32x4 stA[4], stB[4];
  #pragma unroll
  for (int n=0;n<4;n++){
    int R = n*16 + l15;
    f32x4 a_ = {};
    #pragma unroll
    for (int kk=0;kk<2;kk++){
      short8 ka = *(const short8*)&Ks[0][R*64 + (((kk<<2)+lg) ^ (R&7))*8];
      a_ = mfma16(ka, bq[kk], a_);
    }
    stA[n] = a_;
  }
  // no second barrier needed: Ks[0] first overwritten in body 1 (after
  // body 0's end barrier).

  for (int kt = 0; kt < 32; kt += 4){
    AT_BODY(kt+0, 1, 3, 0, 2, stA, stB)
    AT_BODY(kt+1, 2, 0, 1, 3, stB, stA)
    AT_BODY(kt+2, 3, 1, 2, 0, stA, stB)
    AT_BODY(kt+3, 0, 2, 3, 1, stB, stA)
  }

  // write f32 partials: po[kv][bh][qrow][d], pl[kv][bh][qrow]
  const int qrow = qt*128 + w*16 + l15;
  float* pob = po + (((size_t)kv*24 + bh)*4096 + qrow)*64;
  #pragma unroll
  for (int n=0;n<4;n++)
    *(f32x4*)&pob[n*16 + lg*4] = oacc[n];
  if (lg == 0) pl[((size_t)kv*24 + bh)*4096 + qrow] = l_run;
}

// ---------------- combine: o = (O0+O1)/(l0+l1), masked-q -> mean(V) ---------
__global__ __launch_bounds__(256) void comb_k(const float* __restrict__ po,
    const float* __restrict__ pl, const int* __restrict__ mask,
    const float* __restrict__ vm, u16* __restrict__ o)
{
  int row = blockIdx.x;            // b*4096 + s
  int b = row >> 12, s = row & 4095;
  bool fq = mask[row] != 0;
  int t = threadIdx.x;
  #pragma unroll
  for (int i=0;i<3;i++){
    int j = t + i*256;             // 0..767 = h*64 + d
    int h = j >> 6, d = j & 63;
    size_t pi = (((size_t)b*12 + h)*4096 + s)*64 + d;
    size_t li = ((size_t)b*12 + h)*4096 + s;
    float O = po[pi] + po[(size_t)24*4096*64 + pi];
    float L = pl[li] + pl[(size_t)24*4096 + li];
    float v = fq ? O / L : vm[(b*12 + h)*64 + d]*(1.f/4096.f);
    o[(size_t)row*768 + j] = f2b(v);
  }
}

// ---------------------------------------------------------------------------
extern "C" void kernel_launch(void* const* d_in, const int* in_sizes, int n_in,
                              void* d_out, int out_size, void* d_ws, size_t ws_size,
                              hipStream_t stream)
{
  const float* x    = (const float*)d_in[0];
  const float* cosb = (const float*)d_in[1];
  const float* sinb = (const float*)d_in[2];
  const float* c    = (const float*)d_in[3];
  const int* amask  = (const int*)d_in[4];
  const float* ln1w = (const float*)d_in[5];
  const float* Wqkv = (const float*)d_in[6];
  const float* Wout = (const float*)d_in[7];
  const float* ln2w = (const float*)d_in[8];
  const float* W1   = (const float*)d_in[9];
  const float* b1   = (const float*)d_in[10];
  const float* W2   = (const float*)d_in[11];
  const float* b2   = (const float*)d_in[12];
  const float* Wada = (const float*)d_in[13];
  const float* bada = (const float*)d_in[14];

  char* ws = (char*)d_ws;
  size_t off = 0;
  auto take = [&](size_t bytes)->char*{
    char* p = ws + off; off = (off + bytes + 255) & ~(size_t)255; return p;
  };
  float* modb = (float*)take(9216*sizeof(float));
  float* kbias= (float*)take(8192*sizeof(float));
  float* vmean= (float*)take(24*64*sizeof(float));
  u16* hdn  = (u16*)take((size_t)8192*768*2);    // ln1 out; pl aliases; h2 later
  u16* bufA = (u16*)take((size_t)8192*3072*2);   // po aliases; MLP mid later
  u16* vS   = (u16*)take((size_t)8192*768*2);    // v (s-major)
  u16* qTb  = (u16*)take((size_t)8192*768*2);
  u16* kTb  = (u16*)take((size_t)8192*768*2);
  u16* vTb  = (u16*)take((size_t)8192*768*2);    // v (d-major)
  u16* ob   = (u16*)take((size_t)8192*768*2);    // attention output (bf16)
  u16* WqkvB= (u16*)take((size_t)2304*768*2);
  u16* WoutB= (u16*)take((size_t)768*768*2);
  u16* W1B  = (u16*)take((size_t)3072*768*2);
  u16* W2B  = (u16*)take((size_t)768*3072*2);
  float* out = (float*)d_out;
  float* x1 = out;                               // reuse d_out for x1 (f32)
  float* po = (float*)bufA;                      // 2*24*4096*64 f32 = 50.3MB
  float* pl = (float*)hdn;                       // 2*24*4096 f32 = 0.8MB

  cvt4_k<<<6912, 256, 0, stream>>>(Wqkv, WqkvB, Wout, WoutB, W1, W1B, W2, W2B);
  kbias_k<<<32, 256, 0, stream>>>(amask, kbias, vmean, 8192);

  mod_k  <<<2304, 256, 0, stream>>>(c, Wada, bada, modb);
  ln_mod_k<<<8192, 256, 0, stream>>>(x, hdn, ln1w, modb, 0, 1);
  gemm_k<4><<<dim3(64,18), 256, 0, stream>>>(hdn, WqkvB, nullptr, 8192, 2304, 768,
                                             nullptr, nullptr, nullptr,
                                             cosb, sinb, qTb, kTb, vS);
  // hdn (ln1 output) is dead after gemm<4>; bufA unused until MLP -> alias.
  vtr_k  <<<dim3(64,24), 256, 0, stream>>>(vS, vTb, vmean);
  attn_k <<<dim3(32,24,2), 512, 0, stream>>>(qTb, kTb, vTb, kbias, po, pl);
  comb_k <<<8192, 256, 0, stream>>>(po, pl, amask, vmean, ob);
  gemm_k<1><<<dim3(64,6), 256, 0, stream>>>(ob, WoutB, x1, 8192, 768, 768,
                                            x, modb, nullptr,
                                            nullptr, nullptr, nullptr, nullptr, nullptr);
  ln_mod_k<<<8192, 256, 0, stream>>>(x1, hdn, ln2w, modb, 3, 4);
  gemm_k<2><<<dim3(64,24), 256, 0, stream>>>(hdn, W1B, bufA, 8192, 3072, 768,
                                             nullptr, nullptr, b1,
                                             nullptr, nullptr, nullptr, nullptr, nullptr);
  gemm_k<3><<<dim3(64,6), 256, 0, stream>>>(bufA, W2B, out, 8192, 768, 3072,
                                            x1, modb, b2,
                                            nullptr, nullptr, nullptr, nullptr, nullptr);
}

// Round 17
// 368.582 us; speedup vs baseline: 1.6242x; 1.0761x over previous
//
#include <hip/hip_runtime.h>
#include <stdint.h>

// f32 I/O, bf16 MFMA internals. Attention v12 = r16 body (known good) run
// over COMPACTED valid keys only (~50% of 4096): masked keys contribute
// exactly 0 (exp2(-1e30)=0) so gathering valid keys is exact up to FP
// summation order. Keys padded to 512-multiple with zero rows + kb=-1e30.
// No -32 shift needed post-compaction (scores bounded, f32 headroom).
// KV-split x2 with exact partial combine O=(O0+O1)/(l0+l1) (fixed shift=0).
// Masked-q rows = mean(ALL V) via vmean (reference's -1e9 f32 absorption).

typedef unsigned short u16;
typedef __attribute__((ext_vector_type(4))) float f32x4;
typedef __attribute__((ext_vector_type(8))) short short8;
typedef __attribute__((ext_vector_type(4))) short s16x4;
typedef __attribute__((ext_vector_type(8))) __bf16 bf16x8;

__device__ __forceinline__ float b2f(u16 u){
  union { unsigned int i; float f; } v; v.i = ((unsigned int)u) << 16; return v.f;
}
__device__ __forceinline__ u16 f2b(float f){
  union { float f; unsigned int i; } v; v.f = f;
  unsigned int u = v.i;
  u = u + 0x7FFFu + ((u >> 16) & 1u);   // RNE
  return (u16)(u >> 16);
}
__device__ __forceinline__ f32x4 mfma16(short8 a, short8 b, f32x4 c){
  return __builtin_amdgcn_mfma_f32_16x16x32_bf16(
      __builtin_bit_cast(bf16x8, a), __builtin_bit_cast(bf16x8, b), c, 0, 0, 0);
}
__device__ __forceinline__ void gload16(const void* g, void* l){
  void* gnc = const_cast<void*>(g);
  __builtin_amdgcn_global_load_lds((__attribute__((address_space(1))) void*)gnc,
                                   (__attribute__((address_space(3))) void*)l, 16, 0, 0);
}

// ---------------- merged f32 -> bf16 weight conversion (4 segments) ---------
__global__ __launch_bounds__(256) void cvt4_k(
    const float* __restrict__ s0, u16* __restrict__ d0,
    const float* __restrict__ s1, u16* __restrict__ d1,
    const float* __restrict__ s2, u16* __restrict__ d2,
    const float* __restrict__ s3, u16* __restrict__ d3)
{
  int i = blockIdx.x*256 + threadIdx.x;
  const float* src; u16* dst; int j = i;
  if (j < 442368){ src = s0; dst = d0; }
  else if ((j -= 442368) < 147456){ src = s1; dst = d1; }
  else if ((j -= 147456) < 589824){ src = s2; dst = d2; }
  else { j -= 589824; src = s3; dst = d3; }
  float4 v = *(const float4*)(src + (size_t)j*4);
  s16x4 o; o[0]=(short)f2b(v.x); o[1]=(short)f2b(v.y);
  o[2]=(short)f2b(v.z); o[3]=(short)f2b(v.w);
  *(s16x4*)(dst + (size_t)j*4) = o;
}

// ---------------- per-batch valid-key scan (1 wave per batch) ---------------
// idx[b][j] = s of j-th valid key; nvalid[b]; kbc = 0 (valid) / -1e30 (pad);
// block 0 also zeroes vmean accumulators.
__global__ __launch_bounds__(64) void scan_k(const int* __restrict__ mask,
    int* __restrict__ idx, int* __restrict__ nvalid, float* __restrict__ kbc,
    float* __restrict__ vm)
{
  int b = blockIdx.x, l = threadIdx.x;
  const int* m = mask + b*4096;
  int base = 0;
  for (int i0 = 0; i0 < 4096; i0 += 64){
    int v = m[i0 + l] != 0;
    unsigned long long bal = __ballot(v);
    int pre = __popcll(bal & ((1ull << l) - 1ull));
    if (v) idx[b*4096 + base + pre] = i0 + l;
    base += (int)__popcll(bal);
  }
  if (l == 0) nvalid[b] = base;
  for (int i = l; i < 4096; i += 64) kbc[b*4096 + i] = (i < base) ? 0.f : -1e30f;
  if (b == 0) for (int i = l; i < 24*64; i += 64) vm[i] = 0.f;
}

// ---------------- adaLN modulation: mod[b][6*768] = c @ Wada^T + bada --------
__global__ __launch_bounds__(256) void mod_k(const float* __restrict__ c,
    const float* __restrict__ Wada, const float* __restrict__ bada, float* __restrict__ modb)
{
  int o = blockIdx.x*4 + (threadIdx.x >> 6);   // 0..9215
  int l = threadIdx.x & 63;
  int b = o / 4608, j = o - b*4608;
  const float* cp = c + b*768;
  const float* wp = Wada + (size_t)j*768;
  float s = 0.f;
  for (int k = l; k < 768; k += 64) s += cp[k] * wp[k];
  #pragma unroll
  for (int d=1; d<64; d<<=1) s += __shfl_xor(s, d);
  if (l == 0) modb[o] = s + bada[j];
}

// ---------------- LayerNorm (no affine) * w * (1+scale) + shift -> bf16 -----
__global__ __launch_bounds__(256) void ln_mod_k(const float* __restrict__ xin,
    u16* __restrict__ out, const float* __restrict__ lnw, const float* __restrict__ modb,
    int shift_c, int scale_c)
{
  int row = blockIdx.x;             // 0..8191 (b*4096+s)
  int b = row >> 12;
  const float* xp = xin + (size_t)row*768;
  int t = threadIdx.x;
  float v[3]; float s = 0.f, s2 = 0.f;
  #pragma unroll
  for (int i=0;i<3;i++){ float f = xp[t + i*256]; v[i] = f; s += f; s2 += f*f; }
  #pragma unroll
  for (int d=1; d<64; d<<=1){ s += __shfl_xor(s, d); s2 += __shfl_xor(s2, d); }
  __shared__ float rs_[4], rs2_[4];
  int w = t >> 6;
  if ((t & 63) == 0){ rs_[w] = s; rs2_[w] = s2; }
  __syncthreads();
  s  = rs_[0]+rs_[1]+rs_[2]+rs_[3];
  s2 = rs2_[0]+rs2_[1]+rs2_[2]+rs2_[3];
  float mu  = s * (1.f/768.f);
  float var = fmaxf(s2 * (1.f/768.f) - mu*mu, 0.f);
  float rstd = rsqrtf(var + 1e-5f);
  const float* scp = modb + b*4608 + scale_c*768;
  const float* shp = modb + b*4608 + shift_c*768;
  #pragma unroll
  for (int i=0;i<3;i++){
    int d = t + i*256;
    float f = (v[i]-mu)*rstd*lnw[d];
    f = f*(1.f + scp[d]) + shp[d];
    out[(size_t)row*768 + d] = f2b(f);
  }
}

// ---------------- 128x128 BK=64 GEMM, C = A[M,K] @ Bt[N,K]^T, fused epilogues
template<int EPI>
__global__ __launch_bounds__(256) void gemm_k(
    const u16* __restrict__ A, const u16* __restrict__ Bt, void* __restrict__ Cv,
    int M, int N, int K,
    const float* __restrict__ addend, const float* __restrict__ modb,
    const float* __restrict__ bias,
    const float* __restrict__ cosb, const float* __restrict__ sinb,
    u16* __restrict__ qO, u16* __restrict__ kO, u16* __restrict__ vO)
{
  __shared__ __align__(16) u16 As[128*64];
  __shared__ __align__(16) u16 Bs[128*64];
  const int bm = blockIdx.x, bn = blockIdx.y;
  const int tid = threadIdx.x;
  const int w = tid >> 6, l = tid & 63;
  const int wr = w >> 1, wc = w & 1;
  const int l15 = l & 15, lg = l >> 4;
  f32x4 acc[4][4] = {};

  for (int k0 = 0; k0 < K; k0 += 64){
    #pragma unroll
    for (int i=0;i<4;i++){
      int e = i*256 + tid;
      int r = e >> 3, ch = e & 7;
      int sc = ch ^ (r & 7);
      gload16(A  + (size_t)(bm*128 + r)*K + k0 + sc*8, &As[e*8]);
      gload16(Bt + (size_t)(bn*128 + r)*K + k0 + sc*8, &Bs[e*8]);
    }
    __syncthreads();
    #pragma unroll
    for (int kk=0;kk<2;kk++){
      short8 af[4], bfv[4];
      #pragma unroll
      for (int i=0;i<4;i++){
        int ra = wr*64 + i*16 + l15;
        af[i]  = *(const short8*)&As[ra*64 + (((kk*4)+lg) ^ (ra&7))*8];
        int rb = wc*64 + i*16 + l15;
        bfv[i] = *(const short8*)&Bs[rb*64 + (((kk*4)+lg) ^ (rb&7))*8];
      }
      #pragma unroll
      for (int m=0;m<4;m++)
        #pragma unroll
        for (int n=0;n<4;n++)
          acc[m][n] = mfma16(af[m], bfv[n], acc[m][n]);
    }
    __syncthreads();
  }

  if constexpr (EPI == 4){
    const int colseg = bn*128 + wc*64;
    const int qi = colseg / 768;            // 0=q 1=k 2=v
    const int h  = (colseg - qi*768) >> 6;  // 0..11
    const float qs = (qi == 0) ? 0.1803368801111601f : 1.f;  // 0.125*log2(e)
    u16* dst = (qi == 0) ? qO : (qi == 1) ? kO : vO;
    #pragma unroll
    for (int m=0;m<4;m++){
      #pragma unroll
      for (int r=0;r<4;r++){
        int row = bm*128 + wr*64 + m*16 + lg*4 + r;
        int s = row & 4095, bb = row >> 12;
        size_t obase = ((size_t)(bb*12 + h)*4096 + s)*64;
        #pragma unroll
        for (int n2=0;n2<2;n2++){
          int d1 = n2*16 + l15;            // < 32
          int d2 = d1 + 32;
          float c1 = cosb[s*64 + d1], s1 = sinb[s*64 + d1];
          float c2 = cosb[s*64 + d2], s2 = sinb[s*64 + d2];
          float x1 = acc[m][n2][r], x2 = acc[m][n2+2][r];
          dst[obase + d1] = f2b((x1*c1 - x2*s1)*qs);
          dst[obase + d2] = f2b((x2*c2 + x1*s2)*qs);
        }
      }
    }
    return;
  }

  #pragma unroll
  for (int m=0;m<4;m++){
    int row0 = bm*128 + wr*64 + m*16 + lg*4;
    #pragma unroll
    for (int n=0;n<4;n++){
      int col = bn*128 + wc*64 + n*16 + l15;
      #pragma unroll
      for (int r=0;r<4;r++){
        int row = row0 + r;
        size_t idx = (size_t)row*N + col;
        float v = acc[m][n][r];
        if constexpr (EPI == 0){
          ((u16*)Cv)[idx] = f2b(v);
        } else if constexpr (EPI == 1){
          float g = modb[(row>>12)*4608 + 2*768 + col];   // gate_msa
          ((float*)Cv)[idx] = addend[idx] + g*v;
        } else if constexpr (EPI == 2){
          float u = v + bias[col];
          float t0 = 0.7978845608028654f*(u + 0.044715f*u*u*u);
          ((u16*)Cv)[idx] = f2b(0.5f*u*(1.0f + tanhf(t0)));
        } else if constexpr (EPI == 3){
          float g = modb[(row>>12)*4608 + 5*768 + col];   // gate_mlp
          float u = v + bias[col];
          ((float*)Cv)[idx] = addend[idx] + g*u;
        }
      }
    }
  }
}

// ------- gather valid keys: kc rows + V transpose-gather into vTc -----------
__global__ __launch_bounds__(256) void gath_k(const u16* __restrict__ kT,
    const u16* __restrict__ vS, const int* __restrict__ idx,
    const int* __restrict__ nvalid, u16* __restrict__ kc, u16* __restrict__ vTc)
{
  __shared__ __align__(16) u16 tile[64][72];
  int j0 = blockIdx.x*64, bh = blockIdx.y;
  int b = bh / 12;
  int nv = nvalid[b];
  int npad = (nv + 511) & ~511;
  if (j0 >= npad) return;
  int t = threadIdx.x;
  #pragma unroll
  for (int i=0;i<2;i++){
    int e = i*256 + t;
    int r = e >> 3, ch = e & 7;
    int j = j0 + r;
    short8 kv8 = {}, vv8 = {};
    if (j < nv){
      int src = idx[b*4096 + j];
      kv8 = *(const short8*)(kT + ((size_t)bh*4096 + src)*64 + ch*8);
      vv8 = *(const short8*)(vS + ((size_t)bh*4096 + src)*64 + ch*8);
    }
    *(short8*)(kc + ((size_t)bh*4096 + j)*64 + ch*8) = kv8;
    *(short8*)&tile[r][ch*8] = vv8;
  }
  __syncthreads();
  #pragma unroll
  for (int i=0;i<2;i++){
    int e = i*256 + t;
    int dd = e >> 3, s0 = (e & 7)*8;
    short8 ov;
    #pragma unroll
    for (int k2=0;k2<8;k2++) ov[k2] = (short)tile[s0+k2][dd];
    *(short8*)(vTc + ((size_t)bh*64 + dd)*4096 + j0 + s0) = ov;
  }
}

// ---------------- vmean over ALL 4096 V rows (for masked-q rows) ------------
__global__ __launch_bounds__(256) void vmean2_k(const u16* __restrict__ vS,
                                                float* __restrict__ vm)
{
  int bh = blockIdx.y, r0 = blockIdx.x*256;
  int t = threadIdx.x, d = t & 63, g = t >> 6;
  const u16* p = vS + ((size_t)bh*4096 + r0)*64 + d;
  float s = 0.f;
  for (int k = g; k < 256; k += 4) s += b2f(p[(size_t)k*64]);
  __shared__ float red[4][64];
  red[g][d] = s; __syncthreads();
  if (g == 0) atomicAdd(&vm[bh*64 + d], red[0][d]+red[1][d]+red[2][d]+red[3][d]);
}

// ---------------- flash attention: r16 body, compacted keys -----------------
// KQK=(KT+1)%4, KST=(KT+3)%4, VPV=KT%4, VST=(KT+2)%4 (KT relative, < bodies)
#define AT_BODY(KT, KQK, KST, VPV, VST, STC, STN)                              \
{                                                                              \
  f32x4 kb_[4];                                                                \
  _Pragma("unroll")                                                            \
  for (int n=0;n<4;n++)                                                        \
    kb_[n] = *(const f32x4*)(kbrow + (KT)*64 + n*16 + lg*4);                   \
  __builtin_amdgcn_sched_barrier(0);  /* pin kb issue before K/V gloads */     \
  { int k3 = (KT)+3 < bodies ? (KT)+3 : bodies-1;                              \
    gload16(kbase + (size_t)(k3*64+sr)*64 + ssc*8, &Ks[KST][tid*8]); }         \
  { int v2 = (KT)+2 < bodies ? (KT)+2 : bodies-1;                              \
    gload16(vbase + (size_t)sr*4096 + v2*64 + ssc*8, &Vs[VST][tid*8]); }       \
  if ((KT)+1 < bodies){                                                        \
    __builtin_amdgcn_s_setprio(1);                                             \
    _Pragma("unroll")                                                          \
    for (int n=0;n<4;n++){                                                     \
      int R = n*16 + l15;                                                      \
      f32x4 a_ = {};                                                           \
      _Pragma("unroll")                                                        \
      for (int kk=0;kk<2;kk++){                                                \
        short8 ka = *(const short8*)&Ks[KQK][R*64 + (((kk<<2)+lg) ^ (R&7))*8]; \
        a_ = mfma16(ka, bq[kk], a_);                                           \
      }                                                                        \
      STN[n] = a_;                                                             \
    }                                                                          \
    __builtin_amdgcn_s_setprio(0);                                             \
  }                                                                            \
  float p_[4][4]; float ts_ = 0.f;                                             \
  _Pragma("unroll")                                                            \
  for (int n=0;n<4;n++)                                                        \
    _Pragma("unroll")                                                          \
    for (int r=0;r<4;r++){                                                     \
      float e_ = __builtin_amdgcn_exp2f(STC[n][r] + kb_[n][r]);                \
      p_[n][r] = e_; ts_ += e_;                                                \
    }                                                                          \
  ts_ += __shfl_xor(ts_, 16);                                                  \
  ts_ += __shfl_xor(ts_, 32);                                                  \
  l_run += ts_;                                                                \
  _Pragma("unroll")                                                            \
  for (int n=0;n<4;n++){                                                       \
    unsigned p01_, p23_;                                                       \
    asm("v_cvt_pk_bf16_f32 %0, %1, %2" : "=v"(p01_) : "v"(p_[n][0]), "v"(p_[n][1])); \
    asm("v_cvt_pk_bf16_f32 %0, %1, %2" : "=v"(p23_) : "v"(p_[n][2]), "v"(p_[n][3])); \
    int s0_ = n*16 + lg*4;                                                     \
    int off_ = (((s0_>>3) ^ (l15&7))<<3) + (s0_&7);                            \
    *(unsigned*)&Ps[w][l15*64 + off_]     = p01_;                              \
    *(unsigned*)&Ps[w][l15*64 + off_ + 2] = p23_;                              \
  }                                                                            \
  __builtin_amdgcn_s_setprio(1);                                               \
  _Pragma("unroll")                                                            \
  for (int kk=0;kk<2;kk++){                                                    \
    int ch_ = (kk<<2) + lg;                                                    \
    short8 bp_ = *(const short8*)&Ps[w][l15*64 + ((ch_ ^ (l15&7))<<3)];        \
    _Pragma("unroll")                                                          \
    for (int n=0;n<4;n++){                                                     \
      int R = n*16 + l15;                                                      \
      short8 va_ = *(const short8*)&Vs[VPV][R*64 + ((ch_ ^ (R&7))<<3)];        \
      oacc[n] = mfma16(va_, bp_, oacc[n]);                                     \
    }                                                                          \
  }                                                                            \
  __builtin_amdgcn_s_setprio(0);                                               \
  __builtin_amdgcn_s_barrier();                                                \
}

__global__ __launch_bounds__(512) void attn_k(
    const u16* __restrict__ qT, const u16* __restrict__ kc, const u16* __restrict__ vTc,
    const float* __restrict__ kbc, const int* __restrict__ nvalid,
    float* __restrict__ po, float* __restrict__ pl)
{
  __shared__ __align__(16) u16 Ks[4][64*64];
  __shared__ __align__(16) u16 Vs[4][64*64];
  __shared__ __align__(16) u16 Ps[8][16*64];
  const int qt = blockIdx.x, bh = blockIdx.y, kv = blockIdx.z;
  const int b = bh / 12;
  const int tid = threadIdx.x, w = tid >> 6, l = tid & 63;
  const int l15 = l & 15, lg = l >> 4;
  const int nv = nvalid[b];
  const int bodies = ((nv + 511) & ~511) >> 7;   // npad/128 tiles per split
  const int k0 = kv * bodies;                     // tile offset of this split

  short8 bq[2];
  {
    const u16* qp = qT + ((size_t)bh*4096 + qt*128 + w*16 + l15)*64 + lg*8;
    bq[0] = *(const short8*)qp;
    bq[1] = *(const short8*)(qp + 32);
  }
  const float* kbrow = kbc + b*4096 + k0*64;
  const u16* kbase = kc + ((size_t)bh*4096 + (size_t)k0*64)*64;
  const u16* vbase = vTc + (size_t)bh*64*4096 + (size_t)k0*64;

  float l_run = 0.f;
  f32x4 oacc[4] = {};   // O^T[d = n*16+lg*4+r][q = l15]

  const int sr = tid >> 3, ssc = (tid & 7) ^ (sr & 7);

  // prologue: stage K0,K1,K2,V0,V1 (relative); drain; QK^T(0)
  gload16(kbase + (size_t)sr*64 + ssc*8,            &Ks[0][tid*8]);
  gload16(kbase + (size_t)(64+sr)*64 + ssc*8,       &Ks[1][tid*8]);
  gload16(kbase + (size_t)(128+sr)*64 + ssc*8,      &Ks[2][tid*8]);
  gload16(vbase + (size_t)sr*4096 + ssc*8,          &Vs[0][tid*8]);
  gload16(vbase + (size_t)sr*4096 + 64 + ssc*8,     &Vs[1][tid*8]);
  asm volatile("s_waitcnt vmcnt(0)" ::: "memory");
  __builtin_amdgcn_s_barrier();

  f32x4 stA[4], stB[4];
  #pragma unroll
  for (int n=0;n<4;n++){
    int R = n*16 + l15;
    f32x4 a_ = {};
    #pragma unroll
    for (int kk=0;kk<2;kk++){
      short8 ka = *(const short8*)&Ks[0][R*64 + (((kk<<2)+lg) ^ (R&7))*8];
      a_ = mfma16(ka, bq[kk], a_);
    }
    stA[n] = a_;
  }
  // Ks[0] first overwritten in body 1 (after body 0's end barrier).

  for (int kt = 0; kt < bodies; kt += 4){
    AT_BODY(kt+0, 1, 3, 0, 2, stA, stB)
    AT_BODY(kt+1, 2, 0, 1, 3, stB, stA)
    AT_BODY(kt+2, 3, 1, 2, 0, stA, stB)
    AT_BODY(kt+3, 0, 2, 3, 1, stB, stA)
  }

  // write f32 partials: po[kv][bh][qrow][d], pl[kv][bh][qrow]
  const int qrow = qt*128 + w*16 + l15;
  float* pob = po + (((size_t)kv*24 + bh)*4096 + qrow)*64;
  #pragma unroll
  for (int n=0;n<4;n++)
    *(f32x4*)&pob[n*16 + lg*4] = oacc[n];
  if (lg == 0) pl[((size_t)kv*24 + bh)*4096 + qrow] = l_run;
}

// ---------------- combine: o = (O0+O1)/(l0+l1), masked-q -> mean(V) ---------
__global__ __launch_bounds__(256) void comb_k(const float* __restrict__ po,
    const float* __restrict__ pl, const int* __restrict__ mask,
    const float* __restrict__ vm, u16* __restrict__ o)
{
  int row = blockIdx.x;            // b*4096 + s
  int b = row >> 12, s = row & 4095;
  bool fq = mask[row] != 0;
  int t = threadIdx.x;
  #pragma unroll
  for (int i=0;i<3;i++){
    int j = t + i*256;             // 0..767 = h*64 + d
    int h = j >> 6, d = j & 63;
    size_t pi = (((size_t)b*12 + h)*4096 + s)*64 + d;
    size_t li = ((size_t)b*12 + h)*4096 + s;
    float O = po[pi] + po[(size_t)24*4096*64 + pi];
    float L = pl[li] + pl[(size_t)24*4096 + li];
    float v = fq ? O / L : vm[(b*12 + h)*64 + d]*(1.f/4096.f);
    o[(size_t)row*768 + j] = f2b(v);
  }
}

// ---------------------------------------------------------------------------
extern "C" void kernel_launch(void* const* d_in, const int* in_sizes, int n_in,
                              void* d_out, int out_size, void* d_ws, size_t ws_size,
                              hipStream_t stream)
{
  const float* x    = (const float*)d_in[0];
  const float* cosb = (const float*)d_in[1];
  const float* sinb = (const float*)d_in[2];
  const float* c    = (const float*)d_in[3];
  const int* amask  = (const int*)d_in[4];
  const float* ln1w = (const float*)d_in[5];
  const float* Wqkv = (const float*)d_in[6];
  const float* Wout = (const float*)d_in[7];
  const float* ln2w = (const float*)d_in[8];
  const float* W1   = (const float*)d_in[9];
  const float* b1   = (const float*)d_in[10];
  const float* W2   = (const float*)d_in[11];
  const float* b2   = (const float*)d_in[12];
  const float* Wada = (const float*)d_in[13];
  const float* bada = (const float*)d_in[14];

  char* ws = (char*)d_ws;
  size_t off = 0;
  auto take = [&](size_t bytes)->char*{
    char* p = ws + off; off = (off + bytes + 255) & ~(size_t)255; return p;
  };
  float* modb = (float*)take(9216*sizeof(float));
  float* kbc  = (float*)take(8192*sizeof(float));
  float* vmean= (float*)take(24*64*sizeof(float));
  int*   idx  = (int*)take(8192*sizeof(int));
  int*   nvld = (int*)take(2*sizeof(int));
  u16* hdn  = (u16*)take((size_t)8192*768*2);    // ln1 out; pl aliases; h2 later
  u16* bufA = (u16*)take((size_t)8192*3072*2);   // po aliases; MLP mid later
  u16* vS   = (u16*)take((size_t)8192*768*2);    // v (s-major, RoPE'd)
  u16* qTb  = (u16*)take((size_t)8192*768*2);
  u16* kTb  = (u16*)take((size_t)8192*768*2);    // k (s-major, RoPE'd)
  u16* kc   = (u16*)take((size_t)8192*768*2);    // compacted K rows
  u16* vTc  = (u16*)take((size_t)8192*768*2);    // compacted V, d-major
  u16* ob   = (u16*)take((size_t)8192*768*2);    // attention output (bf16)
  u16* WqkvB= (u16*)take((size_t)2304*768*2);
  u16* WoutB= (u16*)take((size_t)768*768*2);
  u16* W1B  = (u16*)take((size_t)3072*768*2);
  u16* W2B  = (u16*)take((size_t)768*3072*2);
  float* out = (float*)d_out;
  float* x1 = out;                               // reuse d_out for x1 (f32)
  float* po = (float*)bufA;                      // 2*24*4096*64 f32 = 50.3MB
  float* pl = (float*)hdn;                       // 2*24*4096 f32 = 0.8MB

  cvt4_k<<<6912, 256, 0, stream>>>(Wqkv, WqkvB, Wout, WoutB, W1, W1B, W2, W2B);
  scan_k<<<2, 64, 0, stream>>>(amask, idx, nvld, kbc, vmean);

  mod_k  <<<2304, 256, 0, stream>>>(c, Wada, bada, modb);
  ln_mod_k<<<8192, 256, 0, stream>>>(x, hdn, ln1w, modb, 0, 1);
  gemm_k<4><<<dim3(64,18), 256, 0, stream>>>(hdn, WqkvB, nullptr, 8192, 2304, 768,
                                             nullptr, nullptr, nullptr,
                                             cosb, sinb, qTb, kTb, vS);
  gath_k <<<dim3(64,24), 256, 0, stream>>>(kTb, vS, idx, nvld, kc, vTc);
  vmean2_k<<<dim3(16,24), 256, 0, stream>>>(vS, vmean);
  attn_k <<<dim3(32,24,2), 512, 0, stream>>>(qTb, kc, vTc, kbc, nvld, po, pl);
  comb_k <<<8192, 256, 0, stream>>>(po, pl, amask, vmean, ob);
  gemm_k<1><<<dim3(64,6), 256, 0, stream>>>(ob, WoutB, x1, 8192, 768, 768,
                                            x, modb, nullptr,
                                            nullptr, nullptr, nullptr, nullptr, nullptr);
  ln_mod_k<<<8192, 256, 0, stream>>>(x1, hdn, ln2w, modb, 3, 4);
  gemm_k<2><<<dim3(64,24), 256, 0, stream>>>(hdn, W1B, bufA, 8192, 3072, 768,
                                             nullptr, nullptr, b1,
                                             nullptr, nullptr, nullptr, nullptr, nullptr);
  gemm_k<3><<<dim3(64,6), 256, 0, stream>>>(bufA, W2B, out, 8192, 768, 3072,
                                            x1, modb, b2,
                                            nullptr, nullptr, nullptr, nullptr, nullptr);
}

// Round 18
// 356.859 us; speedup vs baseline: 1.6776x; 1.0329x over previous
//
#include <hip/hip_runtime.h>
#include <stdint.h>

// f32 I/O, bf16 MFMA internals. Attention v13 = r17 (compacted keys,
// KV-split x2, 4-deep rings) with kb MEMORY LOADS REPLACED by the step
// function j<nv ? 0 : -1e30 evaluated as a wave-uniform 3-way branch:
// full-valid body (plain exp2), straddle body (per-lane select), empty
// body (skip softmax+PV). Explicit s_waitcnt vmcnt(2) replaces the kb
// loads' implicit pipeline regulation (retires prev body's K/V gloads).
// Masked-q rows = mean(ALL V) (reference's -1e9 f32 absorption).

typedef unsigned short u16;
typedef __attribute__((ext_vector_type(4))) float f32x4;
typedef __attribute__((ext_vector_type(8))) short short8;
typedef __attribute__((ext_vector_type(4))) short s16x4;
typedef __attribute__((ext_vector_type(8))) __bf16 bf16x8;

__device__ __forceinline__ float b2f(u16 u){
  union { unsigned int i; float f; } v; v.i = ((unsigned int)u) << 16; return v.f;
}
__device__ __forceinline__ u16 f2b(float f){
  union { float f; unsigned int i; } v; v.f = f;
  unsigned int u = v.i;
  u = u + 0x7FFFu + ((u >> 16) & 1u);   // RNE
  return (u16)(u >> 16);
}
__device__ __forceinline__ f32x4 mfma16(short8 a, short8 b, f32x4 c){
  return __builtin_amdgcn_mfma_f32_16x16x32_bf16(
      __builtin_bit_cast(bf16x8, a), __builtin_bit_cast(bf16x8, b), c, 0, 0, 0);
}
__device__ __forceinline__ void gload16(const void* g, void* l){
  void* gnc = const_cast<void*>(g);
  __builtin_amdgcn_global_load_lds((__attribute__((address_space(1))) void*)gnc,
                                   (__attribute__((address_space(3))) void*)l, 16, 0, 0);
}

// ---------------- merged f32 -> bf16 weight conversion (4 segments) ---------
__global__ __launch_bounds__(256) void cvt4_k(
    const float* __restrict__ s0, u16* __restrict__ d0,
    const float* __restrict__ s1, u16* __restrict__ d1,
    const float* __restrict__ s2, u16* __restrict__ d2,
    const float* __restrict__ s3, u16* __restrict__ d3)
{
  int i = blockIdx.x*256 + threadIdx.x;
  const float* src; u16* dst; int j = i;
  if (j < 442368){ src = s0; dst = d0; }
  else if ((j -= 442368) < 147456){ src = s1; dst = d1; }
  else if ((j -= 147456) < 589824){ src = s2; dst = d2; }
  else { j -= 589824; src = s3; dst = d3; }
  float4 v = *(const float4*)(src + (size_t)j*4);
  s16x4 o; o[0]=(short)f2b(v.x); o[1]=(short)f2b(v.y);
  o[2]=(short)f2b(v.z); o[3]=(short)f2b(v.w);
  *(s16x4*)(dst + (size_t)j*4) = o;
}

// ---------------- per-batch valid-key scan (1 wave per batch) ---------------
__global__ __launch_bounds__(64) void scan_k(const int* __restrict__ mask,
    int* __restrict__ idx, int* __restrict__ nvalid, float* __restrict__ vm)
{
  int b = blockIdx.x, l = threadIdx.x;
  const int* m = mask + b*4096;
  int base = 0;
  for (int i0 = 0; i0 < 4096; i0 += 64){
    int v = m[i0 + l] != 0;
    unsigned long long bal = __ballot(v);
    int pre = __popcll(bal & ((1ull << l) - 1ull));
    if (v) idx[b*4096 + base + pre] = i0 + l;
    base += (int)__popcll(bal);
  }
  if (l == 0) nvalid[b] = base;
  if (b == 0) for (int i = l; i < 24*64; i += 64) vm[i] = 0.f;
}

// ---------------- adaLN modulation: mod[b][6*768] = c @ Wada^T + bada --------
__global__ __launch_bounds__(256) void mod_k(const float* __restrict__ c,
    const float* __restrict__ Wada, const float* __restrict__ bada, float* __restrict__ modb)
{
  int o = blockIdx.x*4 + (threadIdx.x >> 6);   // 0..9215
  int l = threadIdx.x & 63;
  int b = o / 4608, j = o - b*4608;
  const float* cp = c + b*768;
  const float* wp = Wada + (size_t)j*768;
  float s = 0.f;
  for (int k = l; k < 768; k += 64) s += cp[k] * wp[k];
  #pragma unroll
  for (int d=1; d<64; d<<=1) s += __shfl_xor(s, d);
  if (l == 0) modb[o] = s + bada[j];
}

// ---------------- LayerNorm (no affine) * w * (1+scale) + shift -> bf16 -----
__global__ __launch_bounds__(256) void ln_mod_k(const float* __restrict__ xin,
    u16* __restrict__ out, const float* __restrict__ lnw, const float* __restrict__ modb,
    int shift_c, int scale_c)
{
  int row = blockIdx.x;             // 0..8191 (b*4096+s)
  int b = row >> 12;
  const float* xp = xin + (size_t)row*768;
  int t = threadIdx.x;
  float v[3]; float s = 0.f, s2 = 0.f;
  #pragma unroll
  for (int i=0;i<3;i++){ float f = xp[t + i*256]; v[i] = f; s += f; s2 += f*f; }
  #pragma unroll
  for (int d=1; d<64; d<<=1){ s += __shfl_xor(s, d); s2 += __shfl_xor(s2, d); }
  __shared__ float rs_[4], rs2_[4];
  int w = t >> 6;
  if ((t & 63) == 0){ rs_[w] = s; rs2_[w] = s2; }
  __syncthreads();
  s  = rs_[0]+rs_[1]+rs_[2]+rs_[3];
  s2 = rs2_[0]+rs2_[1]+rs2_[2]+rs2_[3];
  float mu  = s * (1.f/768.f);
  float var = fmaxf(s2 * (1.f/768.f) - mu*mu, 0.f);
  float rstd = rsqrtf(var + 1e-5f);
  const float* scp = modb + b*4608 + scale_c*768;
  const float* shp = modb + b*4608 + shift_c*768;
  #pragma unroll
  for (int i=0;i<3;i++){
    int d = t + i*256;
    float f = (v[i]-mu)*rstd*lnw[d];
    f = f*(1.f + scp[d]) + shp[d];
    out[(size_t)row*768 + d] = f2b(f);
  }
}

// ---------------- 128x128 BK=64 GEMM, C = A[M,K] @ Bt[N,K]^T, fused epilogues
template<int EPI>
__global__ __launch_bounds__(256) void gemm_k(
    const u16* __restrict__ A, const u16* __restrict__ Bt, void* __restrict__ Cv,
    int M, int N, int K,
    const float* __restrict__ addend, const float* __restrict__ modb,
    const float* __restrict__ bias,
    const float* __restrict__ cosb, const float* __restrict__ sinb,
    u16* __restrict__ qO, u16* __restrict__ kO, u16* __restrict__ vO)
{
  __shared__ __align__(16) u16 As[128*64];
  __shared__ __align__(16) u16 Bs[128*64];
  const int bm = blockIdx.x, bn = blockIdx.y;
  const int tid = threadIdx.x;
  const int w = tid >> 6, l = tid & 63;
  const int wr = w >> 1, wc = w & 1;
  const int l15 = l & 15, lg = l >> 4;
  f32x4 acc[4][4] = {};

  for (int k0 = 0; k0 < K; k0 += 64){
    #pragma unroll
    for (int i=0;i<4;i++){
      int e = i*256 + tid;
      int r = e >> 3, ch = e & 7;
      int sc = ch ^ (r & 7);
      gload16(A  + (size_t)(bm*128 + r)*K + k0 + sc*8, &As[e*8]);
      gload16(Bt + (size_t)(bn*128 + r)*K + k0 + sc*8, &Bs[e*8]);
    }
    __syncthreads();
    #pragma unroll
    for (int kk=0;kk<2;kk++){
      short8 af[4], bfv[4];
      #pragma unroll
      for (int i=0;i<4;i++){
        int ra = wr*64 + i*16 + l15;
        af[i]  = *(const short8*)&As[ra*64 + (((kk*4)+lg) ^ (ra&7))*8];
        int rb = wc*64 + i*16 + l15;
        bfv[i] = *(const short8*)&Bs[rb*64 + (((kk*4)+lg) ^ (rb&7))*8];
      }
      #pragma unroll
      for (int m=0;m<4;m++)
        #pragma unroll
        for (int n=0;n<4;n++)
          acc[m][n] = mfma16(af[m], bfv[n], acc[m][n]);
    }
    __syncthreads();
  }

  if constexpr (EPI == 4){
    const int colseg = bn*128 + wc*64;
    const int qi = colseg / 768;            // 0=q 1=k 2=v
    const int h  = (colseg - qi*768) >> 6;  // 0..11
    const float qs = (qi == 0) ? 0.1803368801111601f : 1.f;  // 0.125*log2(e)
    u16* dst = (qi == 0) ? qO : (qi == 1) ? kO : vO;
    #pragma unroll
    for (int m=0;m<4;m++){
      #pragma unroll
      for (int r=0;r<4;r++){
        int row = bm*128 + wr*64 + m*16 + lg*4 + r;
        int s = row & 4095, bb = row >> 12;
        size_t obase = ((size_t)(bb*12 + h)*4096 + s)*64;
        #pragma unroll
        for (int n2=0;n2<2;n2++){
          int d1 = n2*16 + l15;            // < 32
          int d2 = d1 + 32;
          float c1 = cosb[s*64 + d1], s1 = sinb[s*64 + d1];
          float c2 = cosb[s*64 + d2], s2 = sinb[s*64 + d2];
          float x1 = acc[m][n2][r], x2 = acc[m][n2+2][r];
          dst[obase + d1] = f2b((x1*c1 - x2*s1)*qs);
          dst[obase + d2] = f2b((x2*c2 + x1*s2)*qs);
        }
      }
    }
    return;
  }

  #pragma unroll
  for (int m=0;m<4;m++){
    int row0 = bm*128 + wr*64 + m*16 + lg*4;
    #pragma unroll
    for (int n=0;n<4;n++){
      int col = bn*128 + wc*64 + n*16 + l15;
      #pragma unroll
      for (int r=0;r<4;r++){
        int row = row0 + r;
        size_t idx = (size_t)row*N + col;
        float v = acc[m][n][r];
        if constexpr (EPI == 0){
          ((u16*)Cv)[idx] = f2b(v);
        } else if constexpr (EPI == 1){
          float g = modb[(row>>12)*4608 + 2*768 + col];   // gate_msa
          ((float*)Cv)[idx] = addend[idx] + g*v;
        } else if constexpr (EPI == 2){
          float u = v + bias[col];
          float t0 = 0.7978845608028654f*(u + 0.044715f*u*u*u);
          ((u16*)Cv)[idx] = f2b(0.5f*u*(1.0f + tanhf(t0)));
        } else if constexpr (EPI == 3){
          float g = modb[(row>>12)*4608 + 5*768 + col];   // gate_mlp
          float u = v + bias[col];
          ((float*)Cv)[idx] = addend[idx] + g*u;
        }
      }
    }
  }
}

// ------- gather valid keys: kc rows + V transpose-gather into vTc -----------
__global__ __launch_bounds__(256) void gath_k(const u16* __restrict__ kT,
    const u16* __restrict__ vS, const int* __restrict__ idx,
    const int* __restrict__ nvalid, u16* __restrict__ kc, u16* __restrict__ vTc)
{
  __shared__ __align__(16) u16 tile[64][72];
  int j0 = blockIdx.x*64, bh = blockIdx.y;
  int b = bh / 12;
  int nv = nvalid[b];
  int npad = (nv + 511) & ~511;
  if (j0 >= npad) return;
  int t = threadIdx.x;
  #pragma unroll
  for (int i=0;i<2;i++){
    int e = i*256 + t;
    int r = e >> 3, ch = e & 7;
    int j = j0 + r;
    short8 kv8 = {}, vv8 = {};
    if (j < nv){
      int src = idx[b*4096 + j];
      kv8 = *(const short8*)(kT + ((size_t)bh*4096 + src)*64 + ch*8);
      vv8 = *(const short8*)(vS + ((size_t)bh*4096 + src)*64 + ch*8);
    }
    *(short8*)(kc + ((size_t)bh*4096 + j)*64 + ch*8) = kv8;
    *(short8*)&tile[r][ch*8] = vv8;
  }
  __syncthreads();
  #pragma unroll
  for (int i=0;i<2;i++){
    int e = i*256 + t;
    int dd = e >> 3, s0 = (e & 7)*8;
    short8 ov;
    #pragma unroll
    for (int k2=0;k2<8;k2++) ov[k2] = (short)tile[s0+k2][dd];
    *(short8*)(vTc + ((size_t)bh*64 + dd)*4096 + j0 + s0) = ov;
  }
}

// ---------------- vmean over ALL 4096 V rows (for masked-q rows) ------------
__global__ __launch_bounds__(256) void vmean2_k(const u16* __restrict__ vS,
                                                float* __restrict__ vm)
{
  int bh = blockIdx.y, r0 = blockIdx.x*256;
  int t = threadIdx.x, d = t & 63, g = t >> 6;
  const u16* p = vS + ((size_t)bh*4096 + r0)*64 + d;
  float s = 0.f;
  for (int k = g; k < 256; k += 4) s += b2f(p[(size_t)k*64]);
  __shared__ float red[4][64];
  red[g][d] = s; __syncthreads();
  if (g == 0) atomicAdd(&vm[bh*64 + d], red[0][d]+red[1][d]+red[2][d]+red[3][d]);
}

// ---------------- flash attention v13: step-function kb, no kb loads --------
// KQK=(KT+1)%4, KST=(KT+3)%4, VPV=KT%4, VST=(KT+2)%4 (KT relative, < bodies)
#define AT_BODY(KT, KQK, KST, VPV, VST, STC, STN)                              \
{                                                                              \
  { int k3 = (KT)+3 < bodies ? (KT)+3 : bodies-1;                              \
    gload16(kbase + (size_t)(k3*64+sr)*64 + ssc*8, &Ks[KST][tid*8]); }         \
  { int v2 = (KT)+2 < bodies ? (KT)+2 : bodies-1;                              \
    gload16(vbase + (size_t)sr*4096 + v2*64 + ssc*8, &Vs[VST][tid*8]); }       \
  asm volatile("s_waitcnt vmcnt(2)" ::: "memory");  /* retire prev K/V */      \
  if ((KT)+1 < bodies){                                                        \
    __builtin_amdgcn_s_setprio(1);                                             \
    _Pragma("unroll")                                                          \
    for (int n=0;n<4;n++){                                                     \
      int R = n*16 + l15;                                                      \
      f32x4 a_ = {};                                                           \
      _Pragma("unroll")                                                        \
      for (int kk=0;kk<2;kk++){                                                \
        short8 ka = *(const short8*)&Ks[KQK][R*64 + (((kk<<2)+lg) ^ (R&7))*8]; \
        a_ = mfma16(ka, bq[kk], a_);                                           \
      }                                                                        \
      STN[n] = a_;                                                             \
    }                                                                          \
    __builtin_amdgcn_s_setprio(0);                                             \
  }                                                                            \
  const int base_ = kbase0 + (KT)*64;                                          \
  if (base_ < nv){                       /* body has at least 1 valid key */   \
    float p_[4][4]; float ts_ = 0.f;                                           \
    if (base_ + 64 <= nv){               /* fully valid (common case) */       \
      _Pragma("unroll")                                                        \
      for (int n=0;n<4;n++)                                                    \
        _Pragma("unroll")                                                      \
        for (int r=0;r<4;r++){                                                 \
          float e_ = __builtin_amdgcn_exp2f(STC[n][r]);                        \
          p_[n][r] = e_; ts_ += e_;                                            \
        }                                                                      \
    } else {                             /* straddle body */                   \
      _Pragma("unroll")                                                        \
      for (int n=0;n<4;n++)                                                    \
        _Pragma("unroll")                                                      \
        for (int r=0;r<4;r++){                                                 \
          int ki_ = base_ + n*16 + lg*4 + r;                                   \
          float e_ = (ki_ < nv) ? __builtin_amdgcn_exp2f(STC[n][r]) : 0.f;     \
          p_[n][r] = e_; ts_ += e_;                                            \
        }                                                                      \
    }                                                                          \
    ts_ += __shfl_xor(ts_, 16);                                                \
    ts_ += __shfl_xor(ts_, 32);                                                \
    l_run += ts_;                                                              \
    _Pragma("unroll")                                                          \
    for (int n=0;n<4;n++){                                                     \
      unsigned p01_, p23_;                                                     \
      asm("v_cvt_pk_bf16_f32 %0, %1, %2" : "=v"(p01_) : "v"(p_[n][0]), "v"(p_[n][1])); \
      asm("v_cvt_pk_bf16_f32 %0, %1, %2" : "=v"(p23_) : "v"(p_[n][2]), "v"(p_[n][3])); \
      int s0_ = n*16 + lg*4;                                                   \
      int off_ = (((s0_>>3) ^ (l15&7))<<3) + (s0_&7);                          \
      *(unsigned*)&Ps[w][l15*64 + off_]     = p01_;                            \
      *(unsigned*)&Ps[w][l15*64 + off_ + 2] = p23_;                            \
    }                                                                          \
    __builtin_amdgcn_s_setprio(1);                                             \
    _Pragma("unroll")                                                          \
    for (int kk=0;kk<2;kk++){                                                  \
      int ch_ = (kk<<2) + lg;                                                  \
      short8 bp_ = *(const short8*)&Ps[w][l15*64 + ((ch_ ^ (l15&7))<<3)];      \
      _Pragma("unroll")                                                        \
      for (int n=0;n<4;n++){                                                   \
        int R = n*16 + l15;                                                    \
        short8 va_ = *(const short8*)&Vs[VPV][R*64 + ((ch_ ^ (R&7))<<3)];      \
        oacc[n] = mfma16(va_, bp_, oacc[n]);                                   \
      }                                                                        \
    }                                                                          \
    __builtin_amdgcn_s_setprio(0);                                             \
  }                                                                            \
  __builtin_amdgcn_s_barrier();                                                \
}

__global__ __launch_bounds__(512) void attn_k(
    const u16* __restrict__ qT, const u16* __restrict__ kc, const u16* __restrict__ vTc,
    const int* __restrict__ nvalid, float* __restrict__ po, float* __restrict__ pl)
{
  __shared__ __align__(16) u16 Ks[4][64*64];
  __shared__ __align__(16) u16 Vs[4][64*64];
  __shared__ __align__(16) u16 Ps[8][16*64];
  const int qt = blockIdx.x, bh = blockIdx.y, kv = blockIdx.z;
  const int b = bh / 12;
  const int tid = threadIdx.x, w = tid >> 6, l = tid & 63;
  const int l15 = l & 15, lg = l >> 4;
  const int nv = nvalid[b];
  const int bodies = ((nv + 511) & ~511) >> 7;   // per-split tile count (mult of 4)
  const int k0 = kv * bodies;                     // tile offset of this split
  const int kbase0 = k0 * 64;                     // key offset of this split

  short8 bq[2];
  {
    const u16* qp = qT + ((size_t)bh*4096 + qt*128 + w*16 + l15)*64 + lg*8;
    bq[0] = *(const short8*)qp;
    bq[1] = *(const short8*)(qp + 32);
  }
  const u16* kbase = kc + ((size_t)bh*4096 + (size_t)kbase0)*64;
  const u16* vbase = vTc + (size_t)bh*64*4096 + (size_t)kbase0;

  float l_run = 0.f;
  f32x4 oacc[4] = {};   // O^T[d = n*16+lg*4+r][q = l15]

  const int sr = tid >> 3, ssc = (tid & 7) ^ (sr & 7);

  // prologue: stage K0,K1,K2,V0,V1 (relative); drain; QK^T(0)
  gload16(kbase + (size_t)sr*64 + ssc*8,            &Ks[0][tid*8]);
  gload16(kbase + (size_t)(64+sr)*64 + ssc*8,       &Ks[1][tid*8]);
  gload16(kbase + (size_t)(128+sr)*64 + ssc*8,      &Ks[2][tid*8]);
  gload16(vbase + (size_t)sr*4096 + ssc*8,          &Vs[0][tid*8]);
  gload16(vbase + (size_t)sr*4096 + 64 + ssc*8,     &Vs[1][tid*8]);
  asm volatile("s_waitcnt vmcnt(0)" ::: "memory");
  __builtin_amdgcn_s_barrier();

  f32x4 stA[4], stB[4];
  #pragma unroll
  for (int n=0;n<4;n++){
    int R = n*16 + l15;
    f32x4 a_ = {};
    #pragma unroll
    for (int kk=0;kk<2;kk++){
      short8 ka = *(const short8*)&Ks[0][R*64 + (((kk<<2)+lg) ^ (R&7))*8];
      a_ = mfma16(ka, bq[kk], a_);
    }
    stA[n] = a_;
  }
  // Ks[0] first overwritten in body 1 (after body 0's end barrier).

  for (int kt = 0; kt < bodies; kt += 4){
    AT_BODY(kt+0, 1, 3, 0, 2, stA, stB)
    AT_BODY(kt+1, 2, 0, 1, 3, stB, stA)
    AT_BODY(kt+2, 3, 1, 2, 0, stA, stB)
    AT_BODY(kt+3, 0, 2, 3, 1, stB, stA)
  }

  // write f32 partials: po[kv][bh][qrow][d], pl[kv][bh][qrow]
  const int qrow = qt*128 + w*16 + l15;
  float* pob = po + (((size_t)kv*24 + bh)*4096 + qrow)*64;
  #pragma unroll
  for (int n=0;n<4;n++)
    *(f32x4*)&pob[n*16 + lg*4] = oacc[n];
  if (lg == 0) pl[((size_t)kv*24 + bh)*4096 + qrow] = l_run;
}

// ---------------- combine: o = (O0+O1)/(l0+l1), masked-q -> mean(V) ---------
__global__ __launch_bounds__(256) void comb_k(const float* __restrict__ po,
    const float* __restrict__ pl, const int* __restrict__ mask,
    const float* __restrict__ vm, u16* __restrict__ o)
{
  int row = blockIdx.x;            // b*4096 + s
  int b = row >> 12, s = row & 4095;
  bool fq = mask[row] != 0;
  int t = threadIdx.x;
  #pragma unroll
  for (int i=0;i<3;i++){
    int j = t + i*256;             // 0..767 = h*64 + d
    int h = j >> 6, d = j & 63;
    size_t pi = (((size_t)b*12 + h)*4096 + s)*64 + d;
    size_t li = ((size_t)b*12 + h)*4096 + s;
    float O = po[pi] + po[(size_t)24*4096*64 + pi];
    float L = pl[li] + pl[(size_t)24*4096 + li];
    float v = fq ? O / L : vm[(b*12 + h)*64 + d]*(1.f/4096.f);
    o[(size_t)row*768 + j] = f2b(v);
  }
}

// ---------------------------------------------------------------------------
extern "C" void kernel_launch(void* const* d_in, const int* in_sizes, int n_in,
                              void* d_out, int out_size, void* d_ws, size_t ws_size,
                              hipStream_t stream)
{
  const float* x    = (const float*)d_in[0];
  const float* cosb = (const float*)d_in[1];
  const float* sinb = (const float*)d_in[2];
  const float* c    = (const float*)d_in[3];
  const int* amask  = (const int*)d_in[4];
  const float* ln1w = (const float*)d_in[5];
  const float* Wqkv = (const float*)d_in[6];
  const float* Wout = (const float*)d_in[7];
  const float* ln2w = (const float*)d_in[8];
  const float* W1   = (const float*)d_in[9];
  const float* b1   = (const float*)d_in[10];
  const float* W2   = (const float*)d_in[11];
  const float* b2   = (const float*)d_in[12];
  const float* Wada = (const float*)d_in[13];
  const float* bada = (const float*)d_in[14];

  char* ws = (char*)d_ws;
  size_t off = 0;
  auto take = [&](size_t bytes)->char*{
    char* p = ws + off; off = (off + bytes + 255) & ~(size_t)255; return p;
  };
  float* modb = (float*)take(9216*sizeof(float));
  float* vmean= (float*)take(24*64*sizeof(float));
  int*   idx  = (int*)take(8192*sizeof(int));
  int*   nvld = (int*)take(2*sizeof(int));
  u16* hdn  = (u16*)take((size_t)8192*768*2);    // ln1 out; pl aliases; h2 later
  u16* bufA = (u16*)take((size_t)8192*3072*2);   // po aliases; MLP mid later
  u16* vS   = (u16*)take((size_t)8192*768*2);    // v (s-major, RoPE'd)
  u16* qTb  = (u16*)take((size_t)8192*768*2);
  u16* kTb  = (u16*)take((size_t)8192*768*2);    // k (s-major, RoPE'd)
  u16* kc   = (u16*)take((size_t)8192*768*2);    // compacted K rows
  u16* vTc  = (u16*)take((size_t)8192*768*2);    // compacted V, d-major
  u16* ob   = (u16*)take((size_t)8192*768*2);    // attention output (bf16)
  u16* WqkvB= (u16*)take((size_t)2304*768*2);
  u16* WoutB= (u16*)take((size_t)768*768*2);
  u16* W1B  = (u16*)take((size_t)3072*768*2);
  u16* W2B  = (u16*)take((size_t)768*3072*2);
  float* out = (float*)d_out;
  float* x1 = out;                               // reuse d_out for x1 (f32)
  float* po = (float*)bufA;                      // 2*24*4096*64 f32 = 50.3MB
  float* pl = (float*)hdn;                       // 2*24*4096 f32 = 0.8MB

  cvt4_k<<<6912, 256, 0, stream>>>(Wqkv, WqkvB, Wout, WoutB, W1, W1B, W2, W2B);
  scan_k<<<2, 64, 0, stream>>>(amask, idx, nvld, vmean);

  mod_k  <<<2304, 256, 0, stream>>>(c, Wada, bada, modb);
  ln_mod_k<<<8192, 256, 0, stream>>>(x, hdn, ln1w, modb, 0, 1);
  gemm_k<4><<<dim3(64,18), 256, 0, stream>>>(hdn, WqkvB, nullptr, 8192, 2304, 768,
                                             nullptr, nullptr, nullptr,
                                             cosb, sinb, qTb, kTb, vS);
  gath_k <<<dim3(64,24), 256, 0, stream>>>(kTb, vS, idx, nvld, kc, vTc);
  vmean2_k<<<dim3(16,24), 256, 0, stream>>>(vS, vmean);
  attn_k <<<dim3(32,24,2), 512, 0, stream>>>(qTb, kc, vTc, nvld, po, pl);
  comb_k <<<8192, 256, 0, stream>>>(po, pl, amask, vmean, ob);
  gemm_k<1><<<dim3(64,6), 256, 0, stream>>>(ob, WoutB, x1, 8192, 768, 768,
                                            x, modb, nullptr,
                                            nullptr, nullptr, nullptr, nullptr, nullptr);
  ln_mod_k<<<8192, 256, 0, stream>>>(x1, hdn, ln2w, modb, 3, 4);
  gemm_k<2><<<dim3(64,24), 256, 0, stream>>>(hdn, W1B, bufA, 8192, 3072, 768,
                                             nullptr, nullptr, b1,
                                             nullptr, nullptr, nullptr, nullptr, nullptr);
  gemm_k<3><<<dim3(64,6), 256, 0, stream>>>(bufA, W2B, out, 8192, 768, 3072,
                                            x1, modb, b2,
                                            nullptr, nullptr, nullptr, nullptr, nullptr);
}